// Round 2
// baseline (477.879 us; speedup 1.0000x reference)
//
#include <hip/hip_runtime.h>
#include <hip/hip_bf16.h>
#include <math.h>

typedef _Float16 f16x8 __attribute__((ext_vector_type(8)));
typedef float f32x4 __attribute__((ext_vector_type(4)));
typedef unsigned short u16;
typedef u16 u16x4 __attribute__((ext_vector_type(4)));

#define DEVI static __device__ __forceinline__
#define LDSS 72  // LDS row stride in f16 elements (+8 pad: conflict-free b128)

DEVI u16 f2h(float f) {
    _Float16 h = (_Float16)f;
    return __builtin_bit_cast(u16, h);
}
DEVI float h2f(u16 u) {
    return (float)__builtin_bit_cast(_Float16, u);
}

DEVI f32x4 mfma16(f16x8 a, f16x8 b, f32x4 c) {
    return __builtin_amdgcn_mfma_f32_16x16x32_f16(a, b, c, 0, 0, 0);
}

// stage an (NR x 64) fp32 tile to f16 LDS (stride LDSS). 256 threads.
template <int NR>
DEVI void stageT(const float* __restrict__ g, int row0, int ldg, int k0, u16* lds) {
    int t = threadIdx.x;
    int c = t & 15;       // 4-float chunk within 64-wide row
    int r0 = t >> 4;      // 0..15
#pragma unroll
    for (int i = 0; i < NR / 16; i++) {
        int r = r0 + i * 16;
        const float* src = g + (size_t)(row0 + r) * ldg + (k0 + c * 4);
        f32x4 f = *reinterpret_cast<const f32x4*>(src);
        u16x4 u;
        u[0] = f2h(f[0]); u[1] = f2h(f[1]); u[2] = f2h(f[2]); u[3] = f2h(f[3]);
        *reinterpret_cast<u16x4*>(&lds[r * LDSS + c * 4]) = u;
    }
}

// ---------------- 128x128 GEMM core: C[m,n] = sum_k A[m,k]*W[n,k] ----------------
DEVI void gemm_core_128(const float* __restrict__ A, const float* __restrict__ W,
                        int K, int lda, int ldw, int m0, int n0,
                        u16* As, u16* Bs, f32x4 acc[4][4]) {
    int lane = threadIdx.x & 63;
    int wid = threadIdx.x >> 6;
    int wm = (wid >> 1) * 64;
    int wn = (wid & 1) * 64;
    int lrow = lane & 15;
    int lk = (lane >> 4) * 8;
    for (int k0 = 0; k0 < K; k0 += 64) {
        __syncthreads();
        stageT<128>(A, m0, lda, k0, As);
        stageT<128>(W, n0, ldw, k0, Bs);
        __syncthreads();
        f16x8 af[2][4], bfr[2][4];
#pragma unroll
        for (int ks = 0; ks < 2; ks++)
#pragma unroll
            for (int i = 0; i < 4; i++) {
                af[ks][i] = *reinterpret_cast<f16x8*>(&As[(wm + i * 16 + lrow) * LDSS + ks * 32 + lk]);
                bfr[ks][i] = *reinterpret_cast<f16x8*>(&Bs[(wn + i * 16 + lrow) * LDSS + ks * 32 + lk]);
            }
#pragma unroll
        for (int ks = 0; ks < 2; ks++)
#pragma unroll
            for (int i = 0; i < 4; i++)
#pragma unroll
                for (int j = 0; j < 4; j++)
                    acc[i][j] = mfma16(af[ks][i], bfr[ks][j], acc[i][j]);
    }
}

// ---------------- QKV: q,k fp32; v f16 ----------------
__global__ __launch_bounds__(256, 2) void qkv_kernel(
    const float* __restrict__ h, const float* __restrict__ Wq,
    const float* __restrict__ Wk, const float* __restrict__ Wv,
    float* __restrict__ qf, float* __restrict__ kf, u16* __restrict__ vb) {
    __shared__ u16 As[128 * LDSS];
    __shared__ u16 Bs[128 * LDSS];
    int z = blockIdx.z;
    const float* W = (z == 0) ? Wq : (z == 1) ? Wk : Wv;
    int m0 = blockIdx.y * 128, n0 = blockIdx.x * 128;
    f32x4 acc[4][4];
    f32x4 zf = {0.f, 0.f, 0.f, 0.f};
#pragma unroll
    for (int i = 0; i < 4; i++)
#pragma unroll
        for (int j = 0; j < 4; j++) acc[i][j] = zf;
    gemm_core_128(h, W, 1024, 1024, 1024, m0, n0, As, Bs, acc);
    int lane = threadIdx.x & 63, wid = threadIdx.x >> 6;
    int wm = (wid >> 1) * 64, wn = (wid & 1) * 64;
    int lrow = lane & 15, lg = lane >> 4;
#pragma unroll
    for (int i = 0; i < 4; i++)
#pragma unroll
        for (int j = 0; j < 4; j++)
#pragma unroll
            for (int r = 0; r < 4; r++) {
                int m = m0 + wm + i * 16 + lg * 4 + r;
                int n = n0 + wn + j * 16 + lrow;
                size_t off = (size_t)m * 1024 + n;
                float v = acc[i][j][r];
                if (z == 0) qf[off] = v;
                else if (z == 1) kf[off] = v;
                else vb[off] = f2h(v);
            }
}

// ---------------- generic 128x64 GEMM, fp32 out, N==1024 ----------------
__global__ __launch_bounds__(256, 2) void gemm_f32_kernel(
    const float* __restrict__ A, const float* __restrict__ W,
    float* __restrict__ out, int K) {
    __shared__ u16 As[128 * LDSS];
    __shared__ u16 Bs[64 * LDSS];
    int m0 = blockIdx.y * 128, n0 = blockIdx.x * 64;
    f32x4 acc[4][2];
    f32x4 zf = {0.f, 0.f, 0.f, 0.f};
#pragma unroll
    for (int i = 0; i < 4; i++) { acc[i][0] = zf; acc[i][1] = zf; }
    int lane = threadIdx.x & 63, wid = threadIdx.x >> 6;
    int wm = (wid >> 1) * 64, wn = (wid & 1) * 32;
    int lrow = lane & 15, lg = lane >> 4, lk = lg * 8;
    for (int k0 = 0; k0 < K; k0 += 64) {
        __syncthreads();
        stageT<128>(A, m0, K, k0, As);
        stageT<64>(W, n0, K, k0, Bs);
        __syncthreads();
#pragma unroll
        for (int ks = 0; ks < 2; ks++) {
            f16x8 a[4];
#pragma unroll
            for (int i = 0; i < 4; i++)
                a[i] = *reinterpret_cast<f16x8*>(&As[(wm + i * 16 + lrow) * LDSS + ks * 32 + lk]);
#pragma unroll
            for (int j = 0; j < 2; j++) {
                f16x8 b = *reinterpret_cast<f16x8*>(&Bs[(wn + j * 16 + lrow) * LDSS + ks * 32 + lk]);
#pragma unroll
                for (int i = 0; i < 4; i++) acc[i][j] = mfma16(a[i], b, acc[i][j]);
            }
        }
    }
#pragma unroll
    for (int i = 0; i < 4; i++)
#pragma unroll
        for (int j = 0; j < 2; j++)
#pragma unroll
            for (int r = 0; r < 4; r++) {
                int m = m0 + wm + i * 16 + lg * 4 + r;
                int n = n0 + wn + j * 16 + lrow;
                out[(size_t)m * 1024 + n] = acc[i][j][r];
            }
}

// ---------------- RoPE + L2 norm + sqk scale, fp32 -> f16 ----------------
__global__ void qkprep_kernel(const float* __restrict__ qf, const float* __restrict__ kf,
                              const float* __restrict__ sqk,
                              u16* __restrict__ qn, u16* __restrict__ kn) {
    const float* src = blockIdx.z ? kf : qf;
    u16* dst = blockIdx.z ? kn : qn;
    int pair = blockIdx.x * 4 + (threadIdx.x >> 6);  // (m,h) pair
    int m = pair >> 4, hh = pair & 15;
    int tt = m & 1023;  // t = m % T
    int d = threadIdx.x & 63;
    size_t off = (size_t)m * 1024 + hh * 64 + d;
    float x = src[off];
    float xn = __shfl_xor(x, 1);
    // emb[t,j]: j even -> sin(t*div[j/2]); j odd -> cos(t*div[j/2]); div[i]=10000^(-i/32)
    // out[2i] = -q[2i+1]*emb[t,32+i] ; out[2i+1] = q[2i]*emb[t,i]
    int j = (d & 1) ? ((d - 1) >> 1) : (32 + (d >> 1));
    float dv = exp2f(-(float)(j >> 1) * 0.41524101186092029f);  // log2(10000)/32
    float ang = (float)tt * dv;
    float e = (j & 1) ? cosf(ang) : sinf(ang);
    float xr = (d & 1) ? (xn * e) : (-xn * e);
    float ss = xr * xr;
#pragma unroll
    for (int o = 1; o < 64; o <<= 1) ss += __shfl_xor(ss, o);
    float sc = rsqrtf(ss) * sqk[hh * 64 + d] * 32.0f;
    dst[off] = f2h(xr * sc);
}

// ---------------- flash attention, gate folded into softmax ----------------
// w = softmax(s)*g / sum(softmax(s)*g) == softmax(s + ln g), ln g = -softplus(-stp*(s-thr))
__global__ __launch_bounds__(256, 2) void attn_kernel(
    const u16* __restrict__ qn, const u16* __restrict__ kn, const u16* __restrict__ vb,
    const float* __restrict__ thr_c, const float* __restrict__ stp,
    float* __restrict__ y) {
    const int T = 1024, C = 1024;
    int qt = blockIdx.x;
    int bh = blockIdx.y;
    int b = bh >> 4, hh = bh & 15;
    int q0 = qt * 64;
    __shared__ u16 Qs[64 * LDSS];
    __shared__ u16 Ks[64 * LDSS];
    __shared__ u16 Vt[64 * LDSS];  // transposed: Vt[d][kv]
    __shared__ u16 Ps[64 * LDSS];  // P[q_local][kv]
    int t = threadIdx.x;
    int lane = t & 63, w = t >> 6;
    int lrow = lane & 15, lg = lane >> 4, lk = lg * 8;

    {  // stage Q (f16 copy)
        int c = t & 15, r0 = t >> 4;
#pragma unroll
        for (int i = 0; i < 4; i++) {
            int r = r0 + i * 16;
            const u16* src = qn + (size_t)(b * T + q0 + r) * C + hh * 64 + c * 4;
            *reinterpret_cast<u16x4*>(&Qs[r * LDSS + c * 4]) = *reinterpret_cast<const u16x4*>(src);
        }
    }
    __syncthreads();
    f16x8 qfr[2];
    qfr[0] = *reinterpret_cast<f16x8*>(&Qs[(w * 16 + lrow) * LDSS + lk]);
    qfr[1] = *reinterpret_cast<f16x8*>(&Qs[(w * 16 + lrow) * LDSS + 32 + lk]);

    float thr = thr_c[hh], st = stp[hh];
    float mrun = -1e30f, den = 0.f;
    f32x4 yacc[4];
    f32x4 zf = {0.f, 0.f, 0.f, 0.f};
#pragma unroll
    for (int i = 0; i < 4; i++) yacc[i] = zf;
    int qg = q0 + w * 16 + lrow;  // this lane's q (as S^T column)

    for (int kt = 0; kt <= qt; kt++) {
        int kv0 = kt * 64;
        __syncthreads();
        {  // stage K
            int c = t & 15, r0 = t >> 4;
#pragma unroll
            for (int i = 0; i < 4; i++) {
                int r = r0 + i * 16;
                const u16* src = kn + (size_t)(b * T + kv0 + r) * C + hh * 64 + c * 4;
                *reinterpret_cast<u16x4*>(&Ks[r * LDSS + c * 4]) = *reinterpret_cast<const u16x4*>(src);
            }
        }
        {  // stage V transposed
            int kv = t & 63, d0 = (t >> 6) * 16;
            const u16* src = vb + (size_t)(b * T + kv0 + kv) * C + hh * 64 + d0;
#pragma unroll
            for (int jj = 0; jj < 4; jj++) {
                u16x4 u = *reinterpret_cast<const u16x4*>(src + jj * 4);
                Vt[(d0 + jj * 4 + 0) * LDSS + kv] = u[0];
                Vt[(d0 + jj * 4 + 1) * LDSS + kv] = u[1];
                Vt[(d0 + jj * 4 + 2) * LDSS + kv] = u[2];
                Vt[(d0 + jj * 4 + 3) * LDSS + kv] = u[3];
            }
        }
        __syncthreads();

        // S^T = K · Q^T : rows kv, cols q
        f32x4 sacc[4];
#pragma unroll
        for (int f = 0; f < 4; f++) sacc[f] = zf;
#pragma unroll
        for (int ks = 0; ks < 2; ks++)
#pragma unroll
            for (int f = 0; f < 4; f++) {
                f16x8 kfr = *reinterpret_cast<f16x8*>(&Ks[(f * 16 + lrow) * LDSS + ks * 32 + lk]);
                sacc[f] = mfma16(kfr, qfr[ks], sacc[f]);
            }

        float svv[16];
        float tmax = -1e30f;
#pragma unroll
        for (int f = 0; f < 4; f++)
#pragma unroll
            for (int r = 0; r < 4; r++) {
                int kvg = kv0 + f * 16 + lg * 4 + r;
                float s = sacc[f][r] * 8.0f;  // * sqrt(D)
                float sp;
                if (kvg > qg) {
                    sp = -1e30f;  // causal mask
                } else {
                    float z = -st * (s - thr);
                    float lg_ = (z > 15.f) ? z : log1pf(__expf(z));  // softplus
                    sp = s - lg_;  // s + ln(gate)
                }
                svv[f * 4 + r] = sp;
                tmax = fmaxf(tmax, sp);
            }
        tmax = fmaxf(tmax, __shfl_xor(tmax, 16));
        tmax = fmaxf(tmax, __shfl_xor(tmax, 32));
        float mnew = fmaxf(mrun, tmax);
        float alpha = __expf(mrun - mnew);
        float tden = 0.f;
        u16 pu[16];
#pragma unroll
        for (int i = 0; i < 16; i++) {
            float p = __expf(svv[i] - mnew);
            u16 ph = f2h(p);
            pu[i] = ph;
            tden += h2f(ph);  // denominator from the quantized P: num/den rounding cancels
        }
        tden += __shfl_xor(tden, 16);
        tden += __shfl_xor(tden, 32);
        den = den * alpha + tden;
        mrun = mnew;

        // write P (q rows, kv contiguous)
#pragma unroll
        for (int f = 0; f < 4; f++) {
            u16x4 u = {pu[f * 4 + 0], pu[f * 4 + 1], pu[f * 4 + 2], pu[f * 4 + 3]};
            *reinterpret_cast<u16x4*>(&Ps[(w * 16 + lrow) * LDSS + f * 16 + lg * 4]) = u;
        }
        // rescale y accumulators (row index = lg*4+r)
        float a4[4];
#pragma unroll
        for (int r = 0; r < 4; r++) a4[r] = __shfl(alpha, lg * 4 + r);
#pragma unroll
        for (int nf = 0; nf < 4; nf++)
#pragma unroll
            for (int r = 0; r < 4; r++) yacc[nf][r] *= a4[r];

        // PV
#pragma unroll
        for (int ks = 0; ks < 2; ks++) {
            f16x8 pf = *reinterpret_cast<f16x8*>(&Ps[(w * 16 + lrow) * LDSS + ks * 32 + lk]);
#pragma unroll
            for (int nf = 0; nf < 4; nf++) {
                f16x8 vf = *reinterpret_cast<f16x8*>(&Vt[(nf * 16 + lrow) * LDSS + ks * 32 + lk]);
                yacc[nf] = mfma16(pf, vf, yacc[nf]);
            }
        }
    }
    float d4[4];
#pragma unroll
    for (int r = 0; r < 4; r++) d4[r] = 1.0f / __shfl(den, lg * 4 + r);
#pragma unroll
    for (int nf = 0; nf < 4; nf++)
#pragma unroll
        for (int r = 0; r < 4; r++) {
            int qrow = q0 + w * 16 + lg * 4 + r;
            y[(size_t)(b * T + qrow) * C + hh * 64 + nf * 16 + lrow] = yacc[nf][r] * d4[r];
        }
}

// ---------------- FC (both halves) + SiLU gate fused ----------------
__global__ __launch_bounds__(256, 2) void fc_silu_kernel(
    const float* __restrict__ h1, const float* __restrict__ Wfc,
    const float* __restrict__ suv, float* __restrict__ xmlp) {
    __shared__ u16 As[128 * LDSS];
    __shared__ u16 BuS[64 * LDSS];
    __shared__ u16 BvS[64 * LDSS];
    int m0 = blockIdx.y * 128, n0 = blockIdx.x * 64;
    f32x4 au[4][2], av[4][2];
    f32x4 zf = {0.f, 0.f, 0.f, 0.f};
#pragma unroll
    for (int i = 0; i < 4; i++) { au[i][0] = zf; au[i][1] = zf; av[i][0] = zf; av[i][1] = zf; }
    int lane = threadIdx.x & 63, wid = threadIdx.x >> 6;
    int wm = (wid >> 1) * 64, wn = (wid & 1) * 32;
    int lrow = lane & 15, lg = lane >> 4, lk = lg * 8;
    for (int k0 = 0; k0 < 1024; k0 += 64) {
        __syncthreads();
        stageT<128>(h1, m0, 1024, k0, As);
        stageT<64>(Wfc, n0, 1024, k0, BuS);
        stageT<64>(Wfc, 4096 + n0, 1024, k0, BvS);
        __syncthreads();
#pragma unroll
        for (int ks = 0; ks < 2; ks++) {
            f16x8 a[4];
#pragma unroll
            for (int i = 0; i < 4; i++)
                a[i] = *reinterpret_cast<f16x8*>(&As[(wm + i * 16 + lrow) * LDSS + ks * 32 + lk]);
#pragma unroll
            for (int j = 0; j < 2; j++) {
                f16x8 bu = *reinterpret_cast<f16x8*>(&BuS[(wn + j * 16 + lrow) * LDSS + ks * 32 + lk]);
                f16x8 bv = *reinterpret_cast<f16x8*>(&BvS[(wn + j * 16 + lrow) * LDSS + ks * 32 + lk]);
#pragma unroll
                for (int i = 0; i < 4; i++) {
                    au[i][j] = mfma16(a[i], bu, au[i][j]);
                    av[i][j] = mfma16(a[i], bv, av[i][j]);
                }
            }
        }
    }
#pragma unroll
    for (int i = 0; i < 4; i++)
#pragma unroll
        for (int j = 0; j < 2; j++) {
            int n = n0 + wn + j * 16 + lrow;
            float su = suv[n] * 32.0f;        // sqrt(C)=32
            float sv2 = suv[4096 + n] * 32.0f;
#pragma unroll
            for (int r = 0; r < 4; r++) {
                int m = m0 + wm + i * 16 + lg * 4 + r;
                float uu = au[i][j][r] * su;
                float vv = av[i][j][r] * sv2;
                float sig = 1.0f / (1.0f + __expf(-vv));
                xmlp[(size_t)m * 4096 + n] = uu * vv * sig;
            }
        }
}

// ---------------- justnorm residual-lerp-justnorm row kernel ----------------
__global__ void normres_kernel(const float* __restrict__ base, const float* __restrict__ delta,
                               const float* __restrict__ alpha, float* __restrict__ out) {
    int row = blockIdx.x;
    int t = threadIdx.x;
    const float* pb = base + (size_t)row * 1024;
    const float* pd = delta + (size_t)row * 1024;
    float xb[4], xd[4];
    float ssb = 0.f, ssd = 0.f;
#pragma unroll
    for (int i = 0; i < 4; i++) {
        xb[i] = pb[t + 256 * i];
        xd[i] = pd[t + 256 * i];
        ssb += xb[i] * xb[i];
        ssd += xd[i] * xd[i];
    }
#pragma unroll
    for (int o = 1; o < 64; o <<= 1) { ssb += __shfl_xor(ssb, o); ssd += __shfl_xor(ssd, o); }
    __shared__ float red[8];
    int w = t >> 6;
    if ((t & 63) == 0) { red[w * 2] = ssb; red[w * 2 + 1] = ssd; }
    __syncthreads();
    ssb = red[0] + red[2] + red[4] + red[6];
    ssd = red[1] + red[3] + red[5] + red[7];
    float rb = rsqrtf(ssb), rd = rsqrtf(ssd);
    float c[4];
    float ssc = 0.f;
#pragma unroll
    for (int i = 0; i < 4; i++) {
        float a = xb[i] * rb;
        float bb = xd[i] * rd;
        float lr = fabsf(alpha[t + 256 * i] * 1.6f);  // 0.05/0.03125
        float cv = a + lr * (bb - a);
        c[i] = cv;
        ssc += cv * cv;
    }
#pragma unroll
    for (int o = 1; o < 64; o <<= 1) ssc += __shfl_xor(ssc, o);
    __syncthreads();
    if ((t & 63) == 0) red[w] = ssc;
    __syncthreads();
    ssc = red[0] + red[1] + red[2] + red[3];
    float rc = rsqrtf(ssc);
#pragma unroll
    for (int i = 0; i < 4; i++) out[(size_t)row * 1024 + t + 256 * i] = c[i] * rc;
}

extern "C" void kernel_launch(void* const* d_in, const int* in_sizes, int n_in,
                              void* d_out, int out_size, void* d_ws, size_t ws_size,
                              hipStream_t stream) {
    const float* h = (const float*)d_in[0];
    const float* Wq = (const float*)d_in[1];
    const float* Wk = (const float*)d_in[2];
    const float* Wv = (const float*)d_in[3];
    const float* Wo = (const float*)d_in[4];
    const float* Wfc = (const float*)d_in[5];
    const float* Wproj = (const float*)d_in[6];
    const float* sqk = (const float*)d_in[7];
    const float* suv = (const float*)d_in[8];
    const float* attn_alpha = (const float*)d_in[9];
    const float* mlp_alpha = (const float*)d_in[10];
    const float* thr_c = (const float*)d_in[11];
    const float* stp = (const float*)d_in[12];

    char* ws = (char*)d_ws;
    float* qf = (float*)(ws + 0);                       // 8MB; later reused as h_att
    float* kf = (float*)(ws + (size_t)(8 << 20));       // 8MB; later reused as h_mlp
    float* y = (float*)(ws + (size_t)(16 << 20));       // 8MB
    float* h1 = (float*)(ws + (size_t)(24 << 20));      // 8MB
    float* xmlp = (float*)(ws + (size_t)(32 << 20));    // 32MB
    u16* qn = (u16*)(ws + (size_t)(64 << 20));          // 4MB (f16)
    u16* kn = (u16*)(ws + (size_t)(68 << 20));          // 4MB (f16)
    u16* vb = (u16*)(ws + (size_t)(72 << 20));          // 4MB (f16)
    float* out = (float*)d_out;

    qkv_kernel<<<dim3(8, 16, 3), 256, 0, stream>>>(h, Wq, Wk, Wv, qf, kf, vb);
    qkprep_kernel<<<dim3(8192, 1, 2), 256, 0, stream>>>(qf, kf, sqk, qn, kn);
    attn_kernel<<<dim3(16, 32), 256, 0, stream>>>(qn, kn, vb, thr_c, stp, y);
    gemm_f32_kernel<<<dim3(16, 16), 256, 0, stream>>>(y, Wo, qf /*h_att*/, 1024);
    normres_kernel<<<dim3(2048), 256, 0, stream>>>(h, qf, attn_alpha, h1);
    fc_silu_kernel<<<dim3(64, 16), 256, 0, stream>>>(h1, Wfc, suv, xmlp);
    gemm_f32_kernel<<<dim3(16, 16), 256, 0, stream>>>(xmlp, Wproj, kf /*h_mlp*/, 4096);
    normres_kernel<<<dim3(2048), 256, 0, stream>>>(h1, kf, mlp_alpha, out);
}

// Round 3
// 295.959 us; speedup vs baseline: 1.6147x; 1.6147x over previous
//
#include <hip/hip_runtime.h>
#include <hip/hip_bf16.h>
#include <math.h>

typedef _Float16 f16x8 __attribute__((ext_vector_type(8)));
typedef float f32x4 __attribute__((ext_vector_type(4)));
typedef unsigned short u16;
typedef u16 u16x4 __attribute__((ext_vector_type(4)));
typedef u16 u16x8 __attribute__((ext_vector_type(8)));

#define DEVI static __device__ __forceinline__
#define LDSS 72  // attn LDS row stride (padded, conflict-free)
#define MB (1u << 20)

DEVI u16 f2h(float f) {
    _Float16 h = (_Float16)f;
    return __builtin_bit_cast(u16, h);
}
DEVI float h2f(u16 u) {
    return (float)__builtin_bit_cast(_Float16, u);
}
DEVI f32x4 mfma16(f16x8 a, f16x8 b, f32x4 c) {
    return __builtin_amdgcn_mfma_f32_16x16x32_f16(a, b, c, 0, 0, 0);
}
DEVI void gload16(const u16* g, u16* l) {
    __builtin_amdgcn_global_load_lds((const __attribute__((address_space(1))) void*)g,
                                     (__attribute__((address_space(3))) void*)l, 16, 0, 0);
}

// stage a 128x64 f16 tile global -> LDS (linear [128][64]) via global_load_lds.
// dest = wave-uniform base + lane*16B (hardware); our linear layout matches exactly.
DEVI void stage128(const u16* __restrict__ g, size_t row0, int ldg, int k0, u16* lds) {
    int t = threadIdx.x;
    const u16* src = g + (row0 + (size_t)(t >> 3)) * (size_t)ldg + k0 + (t & 7) * 8;
    u16* dst = lds + (t >> 6) * 512;  // wave-uniform
#pragma unroll
    for (int is = 0; is < 4; is++)
        gload16(src + (size_t)is * 32 * ldg, dst + is * 2048);
}

// ---------------- 128x128 MFMA core: C[m,n] = sum_k A[m,k]*B[n,k], f16 in ----------------
DEVI void gemm128_core(const u16* __restrict__ A, const u16* __restrict__ B,
                       int ldk, int kbeg, int kend, int m0, int n0,
                       u16* As, u16* Bs, f32x4 acc[4][4]) {
    int lane = threadIdx.x & 63, w = threadIdx.x >> 6;
    int wm = (w >> 1) * 64, wn = (w & 1) * 64;
    int lrow = lane & 15, lg = lane >> 4;
    for (int k0 = kbeg; k0 < kend; k0 += 64) {
        __syncthreads();
        stage128(A, m0, ldk, k0, As);
        stage128(B, n0, ldk, k0, Bs);
        __syncthreads();
#pragma unroll
        for (int ks = 0; ks < 2; ks++) {
            f16x8 af[4], bf[4];
#pragma unroll
            for (int i = 0; i < 4; i++) {
                af[i] = *reinterpret_cast<f16x8*>(&As[(wm + i * 16 + lrow) * 64 + ks * 32 + lg * 8]);
                bf[i] = *reinterpret_cast<f16x8*>(&Bs[(wn + i * 16 + lrow) * 64 + ks * 32 + lg * 8]);
            }
#pragma unroll
            for (int i = 0; i < 4; i++)
#pragma unroll
                for (int j = 0; j < 4; j++)
                    acc[i][j] = mfma16(af[i], bf[j], acc[i][j]);
        }
    }
}

// ---------------- fp32 -> f16 one-time conversion of h + all weights ----------------
__global__ void cvt_kernel(const float* __restrict__ h, const float* __restrict__ Wq,
                           const float* __restrict__ Wk, const float* __restrict__ Wv,
                           const float* __restrict__ Wo, const float* __restrict__ Wfc,
                           const float* __restrict__ Wproj, u16* __restrict__ dst) {
    int bid = blockIdx.x;
    const float* src;
    size_t doff;
    int sb;
    if (bid < 1024)      { src = h;     sb = 0;    doff = 0; }
    else if (bid < 1536) { src = Wq;    sb = 1024; doff = 2097152; }
    else if (bid < 2048) { src = Wk;    sb = 1536; doff = 3145728; }
    else if (bid < 2560) { src = Wv;    sb = 2048; doff = 4194304; }
    else if (bid < 3072) { src = Wo;    sb = 2560; doff = 5242880; }
    else if (bid < 7168) { src = Wfc;   sb = 3072; doff = 10485760; }
    else                 { src = Wproj; sb = 7168; doff = 6291456; }
    size_t idx = (size_t)(bid - sb) * 2048 + threadIdx.x * 8;
    f32x4 a = *reinterpret_cast<const f32x4*>(src + idx);
    f32x4 b = *reinterpret_cast<const f32x4*>(src + idx + 4);
    u16x8 o;
    o[0] = f2h(a[0]); o[1] = f2h(a[1]); o[2] = f2h(a[2]); o[3] = f2h(a[3]);
    o[4] = f2h(b[0]); o[5] = f2h(b[1]); o[6] = f2h(b[2]); o[7] = f2h(b[3]);
    *reinterpret_cast<u16x8*>(dst + doff + idx) = o;
}

// ---------------- QKV ----------------
__global__ __launch_bounds__(256, 2) void qkv_h_kernel(
    const u16* __restrict__ hb, const u16* __restrict__ Wqh, const u16* __restrict__ Wkh,
    const u16* __restrict__ Wvh, u16* __restrict__ qb, u16* __restrict__ kb, u16* __restrict__ vb) {
    __shared__ u16 As[128 * 64];
    __shared__ u16 Bs[128 * 64];
    int z = blockIdx.z;
    const u16* W = (z == 0) ? Wqh : (z == 1) ? Wkh : Wvh;
    u16* dst = (z == 0) ? qb : (z == 1) ? kb : vb;
    int m0 = blockIdx.y * 128, n0 = blockIdx.x * 128;
    f32x4 acc[4][4];
    f32x4 zf = {0.f, 0.f, 0.f, 0.f};
#pragma unroll
    for (int i = 0; i < 4; i++)
#pragma unroll
        for (int j = 0; j < 4; j++) acc[i][j] = zf;
    gemm128_core(hb, W, 1024, 0, 1024, m0, n0, As, Bs, acc);
    int lane = threadIdx.x & 63, w = threadIdx.x >> 6;
    int wm = (w >> 1) * 64, wn = (w & 1) * 64;
    int lrow = lane & 15, lg = lane >> 4;
#pragma unroll
    for (int i = 0; i < 4; i++)
#pragma unroll
        for (int j = 0; j < 4; j++)
#pragma unroll
            for (int r = 0; r < 4; r++) {
                int m = m0 + wm + i * 16 + lg * 4 + r;
                int n = n0 + wn + j * 16 + lrow;
                dst[(size_t)m * 1024 + n] = f2h(acc[i][j][r]);
            }
}

// ---------------- generic 128x128 GEMM, f16 out, optional K-split via grid.z ----------------
__global__ __launch_bounds__(256, 2) void gemm_h_kernel(
    const u16* __restrict__ A, const u16* __restrict__ B, u16* __restrict__ out,
    int ldk, int ksplit, int osplit, int N) {
    __shared__ u16 As[128 * 64];
    __shared__ u16 Bs[128 * 64];
    int z = blockIdx.z;
    int m0 = blockIdx.y * 128, n0 = blockIdx.x * 128;
    f32x4 acc[4][4];
    f32x4 zf = {0.f, 0.f, 0.f, 0.f};
#pragma unroll
    for (int i = 0; i < 4; i++)
#pragma unroll
        for (int j = 0; j < 4; j++) acc[i][j] = zf;
    gemm128_core(A, B, ldk, z * ksplit, (z + 1) * ksplit, m0, n0, As, Bs, acc);
    u16* o = out + (size_t)z * osplit;
    int lane = threadIdx.x & 63, w = threadIdx.x >> 6;
    int wm = (w >> 1) * 64, wn = (w & 1) * 64;
    int lrow = lane & 15, lg = lane >> 4;
#pragma unroll
    for (int i = 0; i < 4; i++)
#pragma unroll
        for (int j = 0; j < 4; j++)
#pragma unroll
            for (int r = 0; r < 4; r++) {
                int m = m0 + wm + i * 16 + lg * 4 + r;
                int n = n0 + wn + j * 16 + lrow;
                o[(size_t)m * N + n] = f2h(acc[i][j][r]);
            }
}

// ---------------- RoPE + L2 norm + sqk scale, f16 in-place ----------------
__global__ void qkprep_kernel(u16* __restrict__ qb, u16* __restrict__ kb,
                              const float* __restrict__ sqk) {
    u16* buf = blockIdx.z ? kb : qb;
    int pair = blockIdx.x * 4 + (threadIdx.x >> 6);  // (m,h) pair
    int m = pair >> 4, hh = pair & 15;
    int tt = m & 1023;  // t = m % T
    int d = threadIdx.x & 63;
    size_t off = (size_t)m * 1024 + hh * 64 + d;
    float x = h2f(buf[off]);
    float xn = __shfl_xor(x, 1);
    // out[2i] = -q[2i+1]*sin-part ; out[2i+1] = q[2i]*cos-part (see round-0 derivation)
    int j = (d & 1) ? ((d - 1) >> 1) : (32 + (d >> 1));
    float dv = exp2f(-(float)(j >> 1) * 0.41524101186092029f);  // log2(10000)/32
    float ang = (float)tt * dv;
    float e = (j & 1) ? cosf(ang) : sinf(ang);
    float xr = (d & 1) ? (xn * e) : (-xn * e);
    float ss = xr * xr;
#pragma unroll
    for (int o = 1; o < 64; o <<= 1) ss += __shfl_xor(ss, o);
    float sc = rsqrtf(ss) * sqk[hh * 64 + d] * 32.0f;
    buf[off] = f2h(xr * sc);
}

// ---------------- flash attention, gate folded into softmax ----------------
__global__ __launch_bounds__(256, 2) void attn_kernel(
    const u16* __restrict__ qb, const u16* __restrict__ kb, const u16* __restrict__ vb,
    const float* __restrict__ thr_c, const float* __restrict__ stp,
    u16* __restrict__ y) {
    const int T = 1024, C = 1024;
    int qt = blockIdx.x;
    int bh = blockIdx.y;
    int b = bh >> 4, hh = bh & 15;
    int q0 = qt * 64;
    __shared__ u16 Qs[64 * LDSS];
    __shared__ u16 Ks[64 * LDSS];
    __shared__ u16 Vt[64 * LDSS];  // transposed: Vt[d][kv]
    __shared__ u16 Ps[64 * LDSS];  // P[q_local][kv]
    int t = threadIdx.x;
    int lane = t & 63, w = t >> 6;
    int lrow = lane & 15, lg = lane >> 4, lk = lg * 8;

    {  // stage Q
        int c = t & 15, r0 = t >> 4;
#pragma unroll
        for (int i = 0; i < 4; i++) {
            int r = r0 + i * 16;
            const u16* src = qb + (size_t)(b * T + q0 + r) * C + hh * 64 + c * 4;
            *reinterpret_cast<u16x4*>(&Qs[r * LDSS + c * 4]) = *reinterpret_cast<const u16x4*>(src);
        }
    }
    __syncthreads();
    f16x8 qfr[2];
    qfr[0] = *reinterpret_cast<f16x8*>(&Qs[(w * 16 + lrow) * LDSS + lk]);
    qfr[1] = *reinterpret_cast<f16x8*>(&Qs[(w * 16 + lrow) * LDSS + 32 + lk]);

    float thr = thr_c[hh], st = stp[hh];
    float mrun = -1e30f, den = 0.f;
    f32x4 yacc[4];
    f32x4 zf = {0.f, 0.f, 0.f, 0.f};
#pragma unroll
    for (int i = 0; i < 4; i++) yacc[i] = zf;
    int qg = q0 + w * 16 + lrow;

    for (int kt = 0; kt <= qt; kt++) {
        int kv0 = kt * 64;
        __syncthreads();
        {  // stage K
            int c = t & 15, r0 = t >> 4;
#pragma unroll
            for (int i = 0; i < 4; i++) {
                int r = r0 + i * 16;
                const u16* src = kb + (size_t)(b * T + kv0 + r) * C + hh * 64 + c * 4;
                *reinterpret_cast<u16x4*>(&Ks[r * LDSS + c * 4]) = *reinterpret_cast<const u16x4*>(src);
            }
        }
        {  // stage V transposed
            int kv = t & 63, d0 = (t >> 6) * 16;
            const u16* src = vb + (size_t)(b * T + kv0 + kv) * C + hh * 64 + d0;
#pragma unroll
            for (int jj = 0; jj < 4; jj++) {
                u16x4 u = *reinterpret_cast<const u16x4*>(src + jj * 4);
                Vt[(d0 + jj * 4 + 0) * LDSS + kv] = u[0];
                Vt[(d0 + jj * 4 + 1) * LDSS + kv] = u[1];
                Vt[(d0 + jj * 4 + 2) * LDSS + kv] = u[2];
                Vt[(d0 + jj * 4 + 3) * LDSS + kv] = u[3];
            }
        }
        __syncthreads();

        // S^T = K · Q^T
        f32x4 sacc[4];
#pragma unroll
        for (int f = 0; f < 4; f++) sacc[f] = zf;
#pragma unroll
        for (int ks = 0; ks < 2; ks++)
#pragma unroll
            for (int f = 0; f < 4; f++) {
                f16x8 kfr = *reinterpret_cast<f16x8*>(&Ks[(f * 16 + lrow) * LDSS + ks * 32 + lk]);
                sacc[f] = mfma16(kfr, qfr[ks], sacc[f]);
            }

        float svv[16];
        float tmax = -1e30f;
#pragma unroll
        for (int f = 0; f < 4; f++)
#pragma unroll
            for (int r = 0; r < 4; r++) {
                int kvg = kv0 + f * 16 + lg * 4 + r;
                float s = sacc[f][r] * 8.0f;  // * sqrt(D)
                float sp;
                if (kvg > qg) {
                    sp = -1e30f;
                } else {
                    float z = -st * (s - thr);
                    float lg_ = (z > 15.f) ? z : log1pf(__expf(z));  // softplus
                    sp = s - lg_;  // s + ln(gate)
                }
                svv[f * 4 + r] = sp;
                tmax = fmaxf(tmax, sp);
            }
        tmax = fmaxf(tmax, __shfl_xor(tmax, 16));
        tmax = fmaxf(tmax, __shfl_xor(tmax, 32));
        float mnew = fmaxf(mrun, tmax);
        float alpha = __expf(mrun - mnew);
        float tden = 0.f;
        u16 pu[16];
#pragma unroll
        for (int i = 0; i < 16; i++) {
            float p = __expf(svv[i] - mnew);
            u16 ph = f2h(p);
            pu[i] = ph;
            tden += h2f(ph);  // denominator from quantized P: rounding cancels
        }
        tden += __shfl_xor(tden, 16);
        tden += __shfl_xor(tden, 32);
        den = den * alpha + tden;
        mrun = mnew;

#pragma unroll
        for (int f = 0; f < 4; f++) {
            u16x4 u = {pu[f * 4 + 0], pu[f * 4 + 1], pu[f * 4 + 2], pu[f * 4 + 3]};
            *reinterpret_cast<u16x4*>(&Ps[(w * 16 + lrow) * LDSS + f * 16 + lg * 4]) = u;
        }
        float a4[4];
#pragma unroll
        for (int r = 0; r < 4; r++) a4[r] = __shfl(alpha, lg * 4 + r);
#pragma unroll
        for (int nf = 0; nf < 4; nf++)
#pragma unroll
            for (int r = 0; r < 4; r++) yacc[nf][r] *= a4[r];

#pragma unroll
        for (int ks = 0; ks < 2; ks++) {
            f16x8 pf = *reinterpret_cast<f16x8*>(&Ps[(w * 16 + lrow) * LDSS + ks * 32 + lk]);
#pragma unroll
            for (int nf = 0; nf < 4; nf++) {
                f16x8 vf = *reinterpret_cast<f16x8*>(&Vt[(nf * 16 + lrow) * LDSS + ks * 32 + lk]);
                yacc[nf] = mfma16(pf, vf, yacc[nf]);
            }
        }
    }
    float d4[4];
#pragma unroll
    for (int r = 0; r < 4; r++) d4[r] = 1.0f / __shfl(den, lg * 4 + r);
#pragma unroll
    for (int nf = 0; nf < 4; nf++)
#pragma unroll
        for (int r = 0; r < 4; r++) {
            int qrow = q0 + w * 16 + lg * 4 + r;
            y[(size_t)(b * T + qrow) * C + hh * 64 + nf * 16 + lrow] = f2h(yacc[nf][r] * d4[r]);
        }
}

// ---------------- FC (u and v halves) + SiLU gate fused, 128x128 tile ----------------
__global__ __launch_bounds__(256, 2) void fc_silu_kernel(
    const u16* __restrict__ h1h, const u16* __restrict__ Wfch,
    const float* __restrict__ suv, u16* __restrict__ xmlp) {
    __shared__ u16 As[128 * 64];
    __shared__ u16 Bu[128 * 64];
    __shared__ u16 Bv[128 * 64];
    int m0 = blockIdx.y * 128, n0 = blockIdx.x * 128;
    f32x4 au[4][4], av[4][4];
    f32x4 zf = {0.f, 0.f, 0.f, 0.f};
#pragma unroll
    for (int i = 0; i < 4; i++)
#pragma unroll
        for (int j = 0; j < 4; j++) { au[i][j] = zf; av[i][j] = zf; }
    int lane = threadIdx.x & 63, w = threadIdx.x >> 6;
    int wm = (w >> 1) * 64, wn = (w & 1) * 64;
    int lrow = lane & 15, lg = lane >> 4;
    for (int k0 = 0; k0 < 1024; k0 += 64) {
        __syncthreads();
        stage128(h1h, m0, 1024, k0, As);
        stage128(Wfch, n0, 1024, k0, Bu);
        stage128(Wfch, 4096 + n0, 1024, k0, Bv);
        __syncthreads();
#pragma unroll
        for (int ks = 0; ks < 2; ks++) {
            f16x8 af[4], bu[4], bv[4];
#pragma unroll
            for (int i = 0; i < 4; i++) {
                af[i] = *reinterpret_cast<f16x8*>(&As[(wm + i * 16 + lrow) * 64 + ks * 32 + lg * 8]);
                bu[i] = *reinterpret_cast<f16x8*>(&Bu[(wn + i * 16 + lrow) * 64 + ks * 32 + lg * 8]);
                bv[i] = *reinterpret_cast<f16x8*>(&Bv[(wn + i * 16 + lrow) * 64 + ks * 32 + lg * 8]);
            }
#pragma unroll
            for (int i = 0; i < 4; i++)
#pragma unroll
                for (int j = 0; j < 4; j++) {
                    au[i][j] = mfma16(af[i], bu[j], au[i][j]);
                    av[i][j] = mfma16(af[i], bv[j], av[i][j]);
                }
        }
    }
#pragma unroll
    for (int i = 0; i < 4; i++)
#pragma unroll
        for (int j = 0; j < 4; j++) {
            int n = n0 + wn + j * 16 + lrow;
            float su = suv[n] * 32.0f;
            float sv = suv[4096 + n] * 32.0f;
#pragma unroll
            for (int r = 0; r < 4; r++) {
                int m = m0 + wm + i * 16 + lg * 4 + r;
                float uu = au[i][j][r] * su;
                float vv = av[i][j][r] * sv;
                float sig = 1.0f / (1.0f + __expf(-vv));
                xmlp[(size_t)m * 4096 + n] = f2h(uu * vv * sig);
            }
        }
}

// ---------------- justnorm residual-lerp-justnorm; delta = sum of f16 parts ----------------
__global__ void normres_kernel(const float* __restrict__ base, const u16* __restrict__ dparts,
                               int nparts, int pstride, const float* __restrict__ alpha,
                               float* __restrict__ outf, u16* __restrict__ outh) {
    int row = blockIdx.x;
    int t = threadIdx.x;
    const float* pb = base + (size_t)row * 1024;
    float xb[4], xd[4];
    float ssb = 0.f, ssd = 0.f;
#pragma unroll
    for (int i = 0; i < 4; i++) {
        size_t off = (size_t)row * 1024 + t + 256 * i;
        xb[i] = pb[t + 256 * i];
        float d = 0.f;
        for (int p = 0; p < nparts; p++) d += h2f(dparts[off + (size_t)p * pstride]);
        xd[i] = d;
        ssb += xb[i] * xb[i];
        ssd += xd[i] * xd[i];
    }
#pragma unroll
    for (int o = 1; o < 64; o <<= 1) { ssb += __shfl_xor(ssb, o); ssd += __shfl_xor(ssd, o); }
    __shared__ float red[8];
    int w = t >> 6;
    if ((t & 63) == 0) { red[w * 2] = ssb; red[w * 2 + 1] = ssd; }
    __syncthreads();
    ssb = red[0] + red[2] + red[4] + red[6];
    ssd = red[1] + red[3] + red[5] + red[7];
    float rb = rsqrtf(ssb), rd = rsqrtf(ssd);
    float c[4];
    float ssc = 0.f;
#pragma unroll
    for (int i = 0; i < 4; i++) {
        float a = xb[i] * rb;
        float bb = xd[i] * rd;
        float lr = fabsf(alpha[t + 256 * i] * 1.6f);  // 0.05/0.03125
        float cv = a + lr * (bb - a);
        c[i] = cv;
        ssc += cv * cv;
    }
#pragma unroll
    for (int o = 1; o < 64; o <<= 1) ssc += __shfl_xor(ssc, o);
    __syncthreads();
    if ((t & 63) == 0) red[w] = ssc;
    __syncthreads();
    ssc = red[0] + red[1] + red[2] + red[3];
    float rc = rsqrtf(ssc);
#pragma unroll
    for (int i = 0; i < 4; i++) {
        float v = c[i] * rc;
        size_t off = (size_t)row * 1024 + t + 256 * i;
        outf[off] = v;
        if (outh) outh[off] = f2h(v);
    }
}

extern "C" void kernel_launch(void* const* d_in, const int* in_sizes, int n_in,
                              void* d_out, int out_size, void* d_ws, size_t ws_size,
                              hipStream_t stream) {
    const float* h = (const float*)d_in[0];
    const float* Wq = (const float*)d_in[1];
    const float* Wk = (const float*)d_in[2];
    const float* Wv = (const float*)d_in[3];
    const float* Wo = (const float*)d_in[4];
    const float* Wfc = (const float*)d_in[5];
    const float* Wproj = (const float*)d_in[6];
    const float* sqk = (const float*)d_in[7];
    const float* suv = (const float*)d_in[8];
    const float* attn_alpha = (const float*)d_in[9];
    const float* mlp_alpha = (const float*)d_in[10];
    const float* thr_c = (const float*)d_in[11];
    const float* stp = (const float*)d_in[12];

    char* ws = (char*)d_ws;
    u16* f16heap = (u16*)ws;
    // f16 heap element offsets (see cvt_kernel)
    u16* hb     = f16heap + 0;         // 2048x1024
    u16* Wqh    = f16heap + 2097152;   // 1024x1024
    u16* Wkh    = f16heap + 3145728;
    u16* Wvh    = f16heap + 4194304;
    u16* Woh    = f16heap + 5242880;
    u16* Wprojh = f16heap + 6291456;   // 1024x4096
    u16* Wfch   = f16heap + 10485760;  // 8192x1024 (reused as proj partials after fc)
    u16* parts  = Wfch;                // 4 x (2048x1024) f16 partials
    u16* qb   = (u16*)(ws + (size_t)36 * MB);
    u16* kb   = (u16*)(ws + (size_t)40 * MB);
    u16* vb   = (u16*)(ws + (size_t)44 * MB);
    u16* y    = (u16*)(ws + (size_t)48 * MB);
    u16* hatt = (u16*)(ws + (size_t)52 * MB);
    float* h1 = (float*)(ws + (size_t)56 * MB);
    u16* h1h  = (u16*)(ws + (size_t)64 * MB);
    u16* xmlp = (u16*)(ws + (size_t)36 * MB);  // alias over qb/kb/vb/y (consumed)
    float* out = (float*)d_out;

    cvt_kernel<<<9216, 256, 0, stream>>>(h, Wq, Wk, Wv, Wo, Wfc, Wproj, f16heap);
    qkv_h_kernel<<<dim3(8, 16, 3), 256, 0, stream>>>(hb, Wqh, Wkh, Wvh, qb, kb, vb);
    qkprep_kernel<<<dim3(8192, 1, 2), 256, 0, stream>>>(qb, kb, sqk);
    attn_kernel<<<dim3(16, 32), 256, 0, stream>>>(qb, kb, vb, thr_c, stp, y);
    gemm_h_kernel<<<dim3(8, 16, 1), 256, 0, stream>>>(y, Woh, hatt, 1024, 1024, 0, 1024);
    normres_kernel<<<2048, 256, 0, stream>>>(h, hatt, 1, 0, attn_alpha, h1, h1h);
    fc_silu_kernel<<<dim3(32, 16), 256, 0, stream>>>(h1h, Wfch, suv, xmlp);
    gemm_h_kernel<<<dim3(8, 16, 4), 256, 0, stream>>>(xmlp, Wprojh, parts, 4096, 1024, 2097152, 1024);
    normres_kernel<<<2048, 256, 0, stream>>>(h1, parts, 4, 2097152, mlp_alpha, out, (u16*)nullptr);
}

// Round 4
// 214.675 us; speedup vs baseline: 2.2261x; 1.3786x over previous
//
#include <hip/hip_runtime.h>
#include <hip/hip_bf16.h>
#include <math.h>

typedef _Float16 f16x8 __attribute__((ext_vector_type(8)));
typedef float f32x4 __attribute__((ext_vector_type(4)));
typedef unsigned short u16;
typedef unsigned int u32;
typedef u16 u16x4 __attribute__((ext_vector_type(4)));
typedef u16 u16x8 __attribute__((ext_vector_type(8)));

#define DEVI static __device__ __forceinline__
#define LDSS 72  // attn LDS row stride (padded, 2-way max on frag reads)
#define MB (1u << 20)

DEVI u16 f2h(float f) {
    _Float16 h = (_Float16)f;
    return __builtin_bit_cast(u16, h);
}
DEVI float h2f(u16 u) {
    return (float)__builtin_bit_cast(_Float16, u);
}
DEVI f32x4 mfma16(f16x8 a, f16x8 b, f32x4 c) {
    return __builtin_amdgcn_mfma_f32_16x16x32_f16(a, b, c, 0, 0, 0);
}
DEVI void gload16(const u16* g, u16* l) {
    __builtin_amdgcn_global_load_lds((const __attribute__((address_space(1))) void*)g,
                                     (__attribute__((address_space(3))) void*)l, 16, 0, 0);
}

// stage a 128x64 f16 tile global -> LDS (linear [128][64]) via global_load_lds.
DEVI void stage128(const u16* __restrict__ g, size_t row0, int ldg, int k0, u16* lds) {
    int t = threadIdx.x;
    const u16* src = g + (row0 + (size_t)(t >> 3)) * (size_t)ldg + k0 + (t & 7) * 8;
    u16* dst = lds + (t >> 6) * 512;  // wave-uniform
#pragma unroll
    for (int is = 0; is < 4; is++)
        gload16(src + (size_t)is * 32 * ldg, dst + is * 2048);
}

// ---------------- 128x128 MFMA core: C[m,n] = sum_k A[m,k]*B[n,k], f16 in ----------------
DEVI void gemm128_core(const u16* __restrict__ A, const u16* __restrict__ B,
                       int ldk, int kbeg, int kend, int m0, int n0,
                       u16* As, u16* Bs, f32x4 acc[4][4]) {
    int lane = threadIdx.x & 63, w = threadIdx.x >> 6;
    int wm = (w >> 1) * 64, wn = (w & 1) * 64;
    int lrow = lane & 15, lg = lane >> 4;
    for (int k0 = kbeg; k0 < kend; k0 += 64) {
        __syncthreads();
        stage128(A, m0, ldk, k0, As);
        stage128(B, n0, ldk, k0, Bs);
        __syncthreads();
#pragma unroll
        for (int ks = 0; ks < 2; ks++) {
            f16x8 af[4], bf[4];
#pragma unroll
            for (int i = 0; i < 4; i++) {
                af[i] = *reinterpret_cast<f16x8*>(&As[(wm + i * 16 + lrow) * 64 + ks * 32 + lg * 8]);
                bf[i] = *reinterpret_cast<f16x8*>(&Bs[(wn + i * 16 + lrow) * 64 + ks * 32 + lg * 8]);
            }
#pragma unroll
            for (int i = 0; i < 4; i++)
#pragma unroll
                for (int j = 0; j < 4; j++)
                    acc[i][j] = mfma16(af[i], bf[j], acc[i][j]);
        }
    }
}

// ---------------- fp32 -> f16 one-time conversion of h + all weights ----------------
__global__ void cvt_kernel(const float* __restrict__ h, const float* __restrict__ Wq,
                           const float* __restrict__ Wk, const float* __restrict__ Wv,
                           const float* __restrict__ Wo, const float* __restrict__ Wfc,
                           const float* __restrict__ Wproj, u16* __restrict__ dst) {
    int bid = blockIdx.x;
    const float* src;
    size_t doff;
    int sb;
    if (bid < 1024)      { src = h;     sb = 0;    doff = 0; }
    else if (bid < 1536) { src = Wq;    sb = 1024; doff = 2097152; }
    else if (bid < 2048) { src = Wk;    sb = 1536; doff = 3145728; }
    else if (bid < 2560) { src = Wv;    sb = 2048; doff = 4194304; }
    else if (bid < 3072) { src = Wo;    sb = 2560; doff = 5242880; }
    else if (bid < 7168) { src = Wfc;   sb = 3072; doff = 10485760; }
    else                 { src = Wproj; sb = 7168; doff = 6291456; }
    size_t idx = (size_t)(bid - sb) * 2048 + threadIdx.x * 8;
    f32x4 a = *reinterpret_cast<const f32x4*>(src + idx);
    f32x4 b = *reinterpret_cast<const f32x4*>(src + idx + 4);
    u16x8 o;
    o[0] = f2h(a[0]); o[1] = f2h(a[1]); o[2] = f2h(a[2]); o[3] = f2h(a[3]);
    o[4] = f2h(b[0]); o[5] = f2h(b[1]); o[6] = f2h(b[2]); o[7] = f2h(b[3]);
    *reinterpret_cast<u16x8*>(dst + doff + idx) = o;
}

// ---------------- QKV ----------------
__global__ __launch_bounds__(256, 2) void qkv_h_kernel(
    const u16* __restrict__ hb, const u16* __restrict__ Wqh, const u16* __restrict__ Wkh,
    const u16* __restrict__ Wvh, u16* __restrict__ qb, u16* __restrict__ kb, u16* __restrict__ vb) {
    __shared__ u16 As[128 * 64];
    __shared__ u16 Bs[128 * 64];
    int z = blockIdx.z;
    const u16* W = (z == 0) ? Wqh : (z == 1) ? Wkh : Wvh;
    u16* dst = (z == 0) ? qb : (z == 1) ? kb : vb;
    int m0 = blockIdx.y * 128, n0 = blockIdx.x * 128;
    f32x4 acc[4][4];
    f32x4 zf = {0.f, 0.f, 0.f, 0.f};
#pragma unroll
    for (int i = 0; i < 4; i++)
#pragma unroll
        for (int j = 0; j < 4; j++) acc[i][j] = zf;
    gemm128_core(hb, W, 1024, 0, 1024, m0, n0, As, Bs, acc);
    int lane = threadIdx.x & 63, w = threadIdx.x >> 6;
    int wm = (w >> 1) * 64, wn = (w & 1) * 64;
    int lrow = lane & 15, lg = lane >> 4;
#pragma unroll
    for (int i = 0; i < 4; i++)
#pragma unroll
        for (int j = 0; j < 4; j++)
#pragma unroll
            for (int r = 0; r < 4; r++) {
                int m = m0 + wm + i * 16 + lg * 4 + r;
                int n = n0 + wn + j * 16 + lrow;
                dst[(size_t)m * 1024 + n] = f2h(acc[i][j][r]);
            }
}

// ---------------- generic 128x128 GEMM, f16 out, optional K-split via grid.z ----------------
__global__ __launch_bounds__(256, 2) void gemm_h_kernel(
    const u16* __restrict__ A, const u16* __restrict__ B, u16* __restrict__ out,
    int ldk, int ksplit, int osplit, int N) {
    __shared__ u16 As[128 * 64];
    __shared__ u16 Bs[128 * 64];
    int z = blockIdx.z;
    int m0 = blockIdx.y * 128, n0 = blockIdx.x * 128;
    f32x4 acc[4][4];
    f32x4 zf = {0.f, 0.f, 0.f, 0.f};
#pragma unroll
    for (int i = 0; i < 4; i++)
#pragma unroll
        for (int j = 0; j < 4; j++) acc[i][j] = zf;
    gemm128_core(A, B, ldk, z * ksplit, (z + 1) * ksplit, m0, n0, As, Bs, acc);
    u16* o = out + (size_t)z * osplit;
    int lane = threadIdx.x & 63, w = threadIdx.x >> 6;
    int wm = (w >> 1) * 64, wn = (w & 1) * 64;
    int lrow = lane & 15, lg = lane >> 4;
#pragma unroll
    for (int i = 0; i < 4; i++)
#pragma unroll
        for (int j = 0; j < 4; j++)
#pragma unroll
            for (int r = 0; r < 4; r++) {
                int m = m0 + wm + i * 16 + lg * 4 + r;
                int n = n0 + wn + j * 16 + lrow;
                o[(size_t)m * N + n] = f2h(acc[i][j][r]);
            }
}

// ---------------- RoPE + L2 norm + sqk scale, f16 in-place ----------------
__global__ void qkprep_kernel(u16* __restrict__ qb, u16* __restrict__ kb,
                              const float* __restrict__ sqk) {
    u16* buf = blockIdx.z ? kb : qb;
    int pair = blockIdx.x * 4 + (threadIdx.x >> 6);  // (m,h) pair
    int m = pair >> 4, hh = pair & 15;
    int tt = m & 1023;  // t = m % T
    int d = threadIdx.x & 63;
    size_t off = (size_t)m * 1024 + hh * 64 + d;
    float x = h2f(buf[off]);
    float xn = __shfl_xor(x, 1);
    int j = (d & 1) ? ((d - 1) >> 1) : (32 + (d >> 1));
    float dv = exp2f(-(float)(j >> 1) * 0.41524101186092029f);  // log2(10000)/32
    float ang = (float)tt * dv;
    float e = (j & 1) ? cosf(ang) : sinf(ang);
    float xr = (d & 1) ? (xn * e) : (-xn * e);
    float ss = xr * xr;
#pragma unroll
    for (int o = 1; o < 64; o <<= 1) ss += __shfl_xor(ss, o);
    float sc = rsqrtf(ss) * sqk[hh * 64 + d] * 32.0f;
    buf[off] = f2h(xr * sc);
}

// ---------------- flash attention, gate folded: softmax(s - softplus(-stp*(s-thr))) --------
// QBLK=32 (2 waves), KVBLK=64, heavy-first launch, diagonal-only masking.
__global__ __launch_bounds__(128, 2) void attn_kernel(
    const u16* __restrict__ qb, const u16* __restrict__ kb, const u16* __restrict__ vb,
    const float* __restrict__ thr_c, const float* __restrict__ stp,
    u16* __restrict__ y) {
    const int T = 1024, C = 1024;
    int qt = (gridDim.x - 1) - blockIdx.x;  // heavy-first
    int bh = blockIdx.y;
    int b = bh >> 4, hh = bh & 15;
    int q0 = qt * 32;
    int nkt = ((q0 + 31) >> 6) + 1;
    __shared__ u16 Qs[32 * LDSS];
    __shared__ u16 Ks[64 * LDSS];
    __shared__ u16 Vt[64 * LDSS];  // transposed: Vt[d][kv]
    __shared__ u16 Ps[32 * LDSS];  // P[q_local][kv] (wave-private rows)
    int t = threadIdx.x;
    int lane = t & 63, w = t >> 6;
    int lrow = lane & 15, lg = lane >> 4, lk = lg * 8;

    {  // stage Q: 32 rows x 64
        int c = t & 7, r0 = t >> 3;
#pragma unroll
        for (int i = 0; i < 2; i++) {
            int r = r0 + i * 16;
            *reinterpret_cast<u16x8*>(&Qs[r * LDSS + c * 8]) =
                *reinterpret_cast<const u16x8*>(qb + (size_t)(b * T + q0 + r) * C + hh * 64 + c * 8);
        }
    }
    __syncthreads();
    f16x8 qfr[2];
    qfr[0] = *reinterpret_cast<f16x8*>(&Qs[(w * 16 + lrow) * LDSS + lk]);
    qfr[1] = *reinterpret_cast<f16x8*>(&Qs[(w * 16 + lrow) * LDSS + 32 + lk]);

    float thr = thr_c[hh], st = stp[hh];
    float st8 = st * 8.0f, stthr = st * thr;
    float mrun = -1e30f, den = 0.f;
    f32x4 yacc[4];
    f32x4 zf = {0.f, 0.f, 0.f, 0.f};
#pragma unroll
    for (int i = 0; i < 4; i++) yacc[i] = zf;
    int qg = q0 + w * 16 + lrow;

    for (int kt = 0; kt < nkt; kt++) {
        int kv0 = kt << 6;
        __syncthreads();
        {  // stage K: 64 rows x 64
            int c = t & 7, r0 = t >> 3;
#pragma unroll
            for (int i = 0; i < 4; i++) {
                int r = r0 + i * 16;
                *reinterpret_cast<u16x8*>(&Ks[r * LDSS + c * 8]) =
                    *reinterpret_cast<const u16x8*>(kb + (size_t)(b * T + kv0 + r) * C + hh * 64 + c * 8);
            }
        }
        {  // stage V transposed, paired b32 writes
            int kvp = t & 31, db = t >> 5;
            const u16* src = vb + (size_t)(b * T + kv0 + 2 * kvp) * C + hh * 64 + db * 16;
#pragma unroll
            for (int dd = 0; dd < 4; dd++) {
                u16x4 a = *reinterpret_cast<const u16x4*>(src + dd * 4);
                u16x4 bb = *reinterpret_cast<const u16x4*>(src + C + dd * 4);
#pragma unroll
                for (int e = 0; e < 4; e++) {
                    u32 v = (u32)a[e] | ((u32)bb[e] << 16);
                    *reinterpret_cast<u32*>(&Vt[(db * 16 + dd * 4 + e) * LDSS + 2 * kvp]) = v;
                }
            }
        }
        __syncthreads();

        // S^T = K . Q^T  (rows kv, cols q)
        f32x4 sacc[4];
#pragma unroll
        for (int f = 0; f < 4; f++) sacc[f] = zf;
#pragma unroll
        for (int ks = 0; ks < 2; ks++)
#pragma unroll
            for (int f = 0; f < 4; f++) {
                f16x8 kfr = *reinterpret_cast<f16x8*>(&Ks[(f * 16 + lrow) * LDSS + ks * 32 + lk]);
                sacc[f] = mfma16(kfr, qfr[ks], sacc[f]);
            }

        float svv[16];
        float tmax = -1e30f;
        bool last = (kt == nkt - 1);
#pragma unroll
        for (int f = 0; f < 4; f++)
#pragma unroll
            for (int r = 0; r < 4; r++) {
                float sv = sacc[f][r];
                float s = sv * 8.0f;                   // * sqrt(D)
                float z = stthr - st8 * sv;            // -st*(s-thr)
                float l = __logf(1.0f + __expf(z));    // softplus(z), exact for z<=15
                float sp = s - ((z > 15.f) ? z : l);
                if (last) {
                    int kvg = kv0 + f * 16 + lg * 4 + r;
                    if (kvg > qg) sp = -1e30f;
                }
                svv[f * 4 + r] = sp;
                tmax = fmaxf(tmax, sp);
            }
        tmax = fmaxf(tmax, __shfl_xor(tmax, 16));
        tmax = fmaxf(tmax, __shfl_xor(tmax, 32));
        float mnew = fmaxf(mrun, tmax);
        float alpha = __expf(mrun - mnew);
        float tden = 0.f;
        u16 pu[16];
#pragma unroll
        for (int i = 0; i < 16; i++) {
            float p = __expf(svv[i] - mnew);
            u16 ph = f2h(p);
            pu[i] = ph;
            tden += h2f(ph);  // denominator from quantized P: rounding cancels
        }
        tden += __shfl_xor(tden, 16);
        tden += __shfl_xor(tden, 32);
        den = den * alpha + tden;
        mrun = mnew;

#pragma unroll
        for (int f = 0; f < 4; f++) {
            u16x4 u = {pu[f * 4 + 0], pu[f * 4 + 1], pu[f * 4 + 2], pu[f * 4 + 3]};
            *reinterpret_cast<u16x4*>(&Ps[(w * 16 + lrow) * LDSS + f * 16 + lg * 4]) = u;
        }
        float a4[4];
#pragma unroll
        for (int r = 0; r < 4; r++) a4[r] = __shfl(alpha, lg * 4 + r);
#pragma unroll
        for (int nf = 0; nf < 4; nf++)
#pragma unroll
            for (int r = 0; r < 4; r++) yacc[nf][r] *= a4[r];

        // PV (P rows are wave-private: no barrier needed, lgkmcnt orders ds ops)
#pragma unroll
        for (int ks = 0; ks < 2; ks++) {
            f16x8 pf = *reinterpret_cast<f16x8*>(&Ps[(w * 16 + lrow) * LDSS + ks * 32 + lk]);
#pragma unroll
            for (int nf = 0; nf < 4; nf++) {
                f16x8 vf = *reinterpret_cast<f16x8*>(&Vt[(nf * 16 + lrow) * LDSS + ks * 32 + lk]);
                yacc[nf] = mfma16(pf, vf, yacc[nf]);
            }
        }
    }
    float d4[4];
#pragma unroll
    for (int r = 0; r < 4; r++) d4[r] = 1.0f / __shfl(den, lg * 4 + r);
#pragma unroll
    for (int nf = 0; nf < 4; nf++)
#pragma unroll
        for (int r = 0; r < 4; r++) {
            int qrow = q0 + w * 16 + lg * 4 + r;
            y[(size_t)(b * T + qrow) * C + hh * 64 + nf * 16 + lrow] = f2h(yacc[nf][r] * d4[r]);
        }
}

// ---------------- FC (u and v halves) + SiLU gate fused, 128x128 tile ----------------
__global__ __launch_bounds__(256, 2) void fc_silu_kernel(
    const u16* __restrict__ h1h, const u16* __restrict__ Wfch,
    const float* __restrict__ suv, u16* __restrict__ xmlp) {
    __shared__ u16 As[128 * 64];
    __shared__ u16 Bu[128 * 64];
    __shared__ u16 Bv[128 * 64];
    int m0 = blockIdx.y * 128, n0 = blockIdx.x * 128;
    f32x4 au[4][4], av[4][4];
    f32x4 zf = {0.f, 0.f, 0.f, 0.f};
#pragma unroll
    for (int i = 0; i < 4; i++)
#pragma unroll
        for (int j = 0; j < 4; j++) { au[i][j] = zf; av[i][j] = zf; }
    int lane = threadIdx.x & 63, w = threadIdx.x >> 6;
    int wm = (w >> 1) * 64, wn = (w & 1) * 64;
    int lrow = lane & 15, lg = lane >> 4;
    for (int k0 = 0; k0 < 1024; k0 += 64) {
        __syncthreads();
        stage128(h1h, m0, 1024, k0, As);
        stage128(Wfch, n0, 1024, k0, Bu);
        stage128(Wfch, 4096 + n0, 1024, k0, Bv);
        __syncthreads();
#pragma unroll
        for (int ks = 0; ks < 2; ks++) {
            f16x8 af[4], bu[4], bv[4];
#pragma unroll
            for (int i = 0; i < 4; i++) {
                af[i] = *reinterpret_cast<f16x8*>(&As[(wm + i * 16 + lrow) * 64 + ks * 32 + lg * 8]);
                bu[i] = *reinterpret_cast<f16x8*>(&Bu[(wn + i * 16 + lrow) * 64 + ks * 32 + lg * 8]);
                bv[i] = *reinterpret_cast<f16x8*>(&Bv[(wn + i * 16 + lrow) * 64 + ks * 32 + lg * 8]);
            }
#pragma unroll
            for (int i = 0; i < 4; i++)
#pragma unroll
                for (int j = 0; j < 4; j++) {
                    au[i][j] = mfma16(af[i], bu[j], au[i][j]);
                    av[i][j] = mfma16(af[i], bv[j], av[i][j]);
                }
        }
    }
#pragma unroll
    for (int i = 0; i < 4; i++)
#pragma unroll
        for (int j = 0; j < 4; j++) {
            int n = n0 + wn + j * 16 + lrow;
            float su = suv[n] * 32.0f;
            float sv = suv[4096 + n] * 32.0f;
#pragma unroll
            for (int r = 0; r < 4; r++) {
                int m = m0 + wm + i * 16 + lg * 4 + r;
                float uu = au[i][j][r] * su;
                float vv = av[i][j][r] * sv;
                float sig = 1.0f / (1.0f + __expf(-vv));
                xmlp[(size_t)m * 4096 + n] = f2h(uu * vv * sig);
            }
        }
}

// ---------------- justnorm residual-lerp-justnorm; delta = sum of f16 parts ----------------
__global__ void normres_kernel(const float* __restrict__ base, const u16* __restrict__ dparts,
                               int nparts, int pstride, const float* __restrict__ alpha,
                               float* __restrict__ outf, u16* __restrict__ outh) {
    int row = blockIdx.x;
    int t = threadIdx.x;
    const float* pb = base + (size_t)row * 1024;
    float xb[4], xd[4];
    float ssb = 0.f, ssd = 0.f;
#pragma unroll
    for (int i = 0; i < 4; i++) {
        size_t off = (size_t)row * 1024 + t + 256 * i;
        xb[i] = pb[t + 256 * i];
        float d = 0.f;
        for (int p = 0; p < nparts; p++) d += h2f(dparts[off + (size_t)p * pstride]);
        xd[i] = d;
        ssb += xb[i] * xb[i];
        ssd += xd[i] * xd[i];
    }
#pragma unroll
    for (int o = 1; o < 64; o <<= 1) { ssb += __shfl_xor(ssb, o); ssd += __shfl_xor(ssd, o); }
    __shared__ float red[8];
    int w = t >> 6;
    if ((t & 63) == 0) { red[w * 2] = ssb; red[w * 2 + 1] = ssd; }
    __syncthreads();
    ssb = red[0] + red[2] + red[4] + red[6];
    ssd = red[1] + red[3] + red[5] + red[7];
    float rb = rsqrtf(ssb), rd = rsqrtf(ssd);
    float c[4];
    float ssc = 0.f;
#pragma unroll
    for (int i = 0; i < 4; i++) {
        float a = xb[i] * rb;
        float bb = xd[i] * rd;
        float lr = fabsf(alpha[t + 256 * i] * 1.6f);  // 0.05/0.03125
        float cv = a + lr * (bb - a);
        c[i] = cv;
        ssc += cv * cv;
    }
#pragma unroll
    for (int o = 1; o < 64; o <<= 1) ssc += __shfl_xor(ssc, o);
    __syncthreads();
    if ((t & 63) == 0) red[w] = ssc;
    __syncthreads();
    ssc = red[0] + red[1] + red[2] + red[3];
    float rc = rsqrtf(ssc);
#pragma unroll
    for (int i = 0; i < 4; i++) {
        float v = c[i] * rc;
        size_t off = (size_t)row * 1024 + t + 256 * i;
        outf[off] = v;
        if (outh) outh[off] = f2h(v);
    }
}

extern "C" void kernel_launch(void* const* d_in, const int* in_sizes, int n_in,
                              void* d_out, int out_size, void* d_ws, size_t ws_size,
                              hipStream_t stream) {
    const float* h = (const float*)d_in[0];
    const float* Wq = (const float*)d_in[1];
    const float* Wk = (const float*)d_in[2];
    const float* Wv = (const float*)d_in[3];
    const float* Wo = (const float*)d_in[4];
    const float* Wfc = (const float*)d_in[5];
    const float* Wproj = (const float*)d_in[6];
    const float* sqk = (const float*)d_in[7];
    const float* suv = (const float*)d_in[8];
    const float* attn_alpha = (const float*)d_in[9];
    const float* mlp_alpha = (const float*)d_in[10];
    const float* thr_c = (const float*)d_in[11];
    const float* stp = (const float*)d_in[12];

    char* ws = (char*)d_ws;
    u16* f16heap = (u16*)ws;
    u16* hb     = f16heap + 0;         // 2048x1024       ( 0..4MB)
    u16* Wqh    = f16heap + 2097152;   // 1024x1024       ( 4..6MB)
    u16* Wkh    = f16heap + 3145728;   //                 ( 6..8MB)
    u16* Wvh    = f16heap + 4194304;   //                 ( 8..10MB)
    u16* Woh    = f16heap + 5242880;   //                 (10..12MB)
    u16* Wprojh = f16heap + 6291456;   // 1024x4096       (12..20MB)
    u16* Wfch   = f16heap + 10485760;  // 8192x1024       (20..36MB; reused as proj partials)
    u16* partsP = Wfch;                // 4 x (2048x1024) proj partials
    u16* qb   = (u16*)(ws + (size_t)36 * MB);
    u16* kb   = (u16*)(ws + (size_t)40 * MB);
    u16* vb   = (u16*)(ws + (size_t)44 * MB);
    u16* y    = (u16*)(ws + (size_t)48 * MB);
    u16* hattP = qb;                   // 2 x (2048x1024) Wo partials (qb/kb region, free post-attn)
    float* h1 = (float*)(ws + (size_t)56 * MB);
    u16* h1h  = (u16*)(ws + (size_t)64 * MB);
    u16* xmlp = (u16*)(ws + (size_t)36 * MB);  // alias over qb..y (consumed)
    float* out = (float*)d_out;

    cvt_kernel<<<9216, 256, 0, stream>>>(h, Wq, Wk, Wv, Wo, Wfc, Wproj, f16heap);
    qkv_h_kernel<<<dim3(8, 16, 3), 256, 0, stream>>>(hb, Wqh, Wkh, Wvh, qb, kb, vb);
    qkprep_kernel<<<dim3(8192, 1, 2), 256, 0, stream>>>(qb, kb, sqk);
    attn_kernel<<<dim3(32, 32), 128, 0, stream>>>(qb, kb, vb, thr_c, stp, y);
    gemm_h_kernel<<<dim3(8, 16, 2), 256, 0, stream>>>(y, Woh, hattP, 1024, 512, 2097152, 1024);
    normres_kernel<<<2048, 256, 0, stream>>>(h, hattP, 2, 2097152, attn_alpha, h1, h1h);
    fc_silu_kernel<<<dim3(32, 16), 256, 0, stream>>>(h1h, Wfch, suv, xmlp);
    gemm_h_kernel<<<dim3(8, 16, 4), 256, 0, stream>>>(xmlp, Wprojh, partsP, 4096, 1024, 2097152, 1024);
    normres_kernel<<<2048, 256, 0, stream>>>(h1, partsP, 4, 2097152, mlp_alpha, out, (u16*)nullptr);
}

// Round 5
// 209.956 us; speedup vs baseline: 2.2761x; 1.0225x over previous
//
#include <hip/hip_runtime.h>
#include <hip/hip_bf16.h>
#include <math.h>

typedef _Float16 f16x8 __attribute__((ext_vector_type(8)));
typedef float f32x4 __attribute__((ext_vector_type(4)));
typedef float f32x2 __attribute__((ext_vector_type(2)));
typedef unsigned short u16;
typedef unsigned int u32;
typedef u16 u16x4 __attribute__((ext_vector_type(4)));
typedef u16 u16x8 __attribute__((ext_vector_type(8)));

#define DEVI static __device__ __forceinline__
#define LDSS 72  // attn LDS row stride (padded)
#define MB (1u << 20)

DEVI u16 f2h(float f) {
    _Float16 h = (_Float16)f;
    return __builtin_bit_cast(u16, h);
}
DEVI float h2f(u16 u) {
    return (float)__builtin_bit_cast(_Float16, u);
}
DEVI f32x4 mfma16(f16x8 a, f16x8 b, f32x4 c) {
    return __builtin_amdgcn_mfma_f32_16x16x32_f16(a, b, c, 0, 0, 0);
}
DEVI void gload16(const u16* g, u16* l) {
    __builtin_amdgcn_global_load_lds((const __attribute__((address_space(1))) void*)g,
                                     (__attribute__((address_space(3))) void*)l, 16, 0, 0);
}

// stage a 128x64 f16 tile global -> LDS (linear [128][64]) via global_load_lds.
DEVI void stage128(const u16* __restrict__ g, size_t row0, int ldg, int k0, u16* lds) {
    int t = threadIdx.x;
    const u16* src = g + (row0 + (size_t)(t >> 3)) * (size_t)ldg + k0 + (t & 7) * 8;
    u16* dst = lds + (t >> 6) * 512;  // wave-uniform
#pragma unroll
    for (int is = 0; is < 4; is++)
        gload16(src + (size_t)is * 32 * ldg, dst + is * 2048);
}

// ---------------- 128x128 MFMA core: C[m,n] = sum_k A[m,k]*B[n,k], f16 in ----------------
DEVI void gemm128_core(const u16* __restrict__ A, const u16* __restrict__ B,
                       int ldk, int kbeg, int kend, int m0, int n0,
                       u16* As, u16* Bs, f32x4 acc[4][4]) {
    int lane = threadIdx.x & 63, w = threadIdx.x >> 6;
    int wm = (w >> 1) * 64, wn = (w & 1) * 64;
    int lrow = lane & 15, lg = lane >> 4;
    for (int k0 = kbeg; k0 < kend; k0 += 64) {
        __syncthreads();
        stage128(A, m0, ldk, k0, As);
        stage128(B, n0, ldk, k0, Bs);
        __syncthreads();
#pragma unroll
        for (int ks = 0; ks < 2; ks++) {
            f16x8 af[4], bf[4];
#pragma unroll
            for (int i = 0; i < 4; i++) {
                af[i] = *reinterpret_cast<f16x8*>(&As[(wm + i * 16 + lrow) * 64 + ks * 32 + lg * 8]);
                bf[i] = *reinterpret_cast<f16x8*>(&Bs[(wn + i * 16 + lrow) * 64 + ks * 32 + lg * 8]);
            }
#pragma unroll
            for (int i = 0; i < 4; i++)
#pragma unroll
                for (int j = 0; j < 4; j++)
                    acc[i][j] = mfma16(af[i], bf[j], acc[i][j]);
        }
    }
}

// ---------------- fp32 -> f16 one-time conversion of h + all weights ----------------
__global__ void cvt_kernel(const float* __restrict__ h, const float* __restrict__ Wq,
                           const float* __restrict__ Wk, const float* __restrict__ Wv,
                           const float* __restrict__ Wo, const float* __restrict__ Wfc,
                           const float* __restrict__ Wproj, u16* __restrict__ dst) {
    int bid = blockIdx.x;
    const float* src;
    size_t doff;
    int sb;
    if (bid < 1024)      { src = h;     sb = 0;    doff = 0; }
    else if (bid < 1536) { src = Wq;    sb = 1024; doff = 2097152; }
    else if (bid < 2048) { src = Wk;    sb = 1536; doff = 3145728; }
    else if (bid < 2560) { src = Wv;    sb = 2048; doff = 4194304; }
    else if (bid < 3072) { src = Wo;    sb = 2560; doff = 5242880; }
    else if (bid < 7168) { src = Wfc;   sb = 3072; doff = 10485760; }
    else                 { src = Wproj; sb = 7168; doff = 6291456; }
    size_t idx = (size_t)(bid - sb) * 2048 + threadIdx.x * 8;
    f32x4 a = *reinterpret_cast<const f32x4*>(src + idx);
    f32x4 b = *reinterpret_cast<const f32x4*>(src + idx + 4);
    u16x8 o;
    o[0] = f2h(a[0]); o[1] = f2h(a[1]); o[2] = f2h(a[2]); o[3] = f2h(a[3]);
    o[4] = f2h(b[0]); o[5] = f2h(b[1]); o[6] = f2h(b[2]); o[7] = f2h(b[3]);
    *reinterpret_cast<u16x8*>(dst + doff + idx) = o;
}

// ---------------- QKV ----------------
__global__ __launch_bounds__(256, 2) void qkv_h_kernel(
    const u16* __restrict__ hb, const u16* __restrict__ Wqh, const u16* __restrict__ Wkh,
    const u16* __restrict__ Wvh, u16* __restrict__ qb, u16* __restrict__ kb, u16* __restrict__ vb) {
    __shared__ u16 As[128 * 64];
    __shared__ u16 Bs[128 * 64];
    int z = blockIdx.z;
    const u16* W = (z == 0) ? Wqh : (z == 1) ? Wkh : Wvh;
    u16* dst = (z == 0) ? qb : (z == 1) ? kb : vb;
    int m0 = blockIdx.y * 128, n0 = blockIdx.x * 128;
    f32x4 acc[4][4];
    f32x4 zf = {0.f, 0.f, 0.f, 0.f};
#pragma unroll
    for (int i = 0; i < 4; i++)
#pragma unroll
        for (int j = 0; j < 4; j++) acc[i][j] = zf;
    gemm128_core(hb, W, 1024, 0, 1024, m0, n0, As, Bs, acc);
    int lane = threadIdx.x & 63, w = threadIdx.x >> 6;
    int wm = (w >> 1) * 64, wn = (w & 1) * 64;
    int lrow = lane & 15, lg = lane >> 4;
#pragma unroll
    for (int i = 0; i < 4; i++)
#pragma unroll
        for (int j = 0; j < 4; j++)
#pragma unroll
            for (int r = 0; r < 4; r++) {
                int m = m0 + wm + i * 16 + lg * 4 + r;
                int n = n0 + wn + j * 16 + lrow;
                dst[(size_t)m * 1024 + n] = f2h(acc[i][j][r]);
            }
}

// ---------------- generic 128x128 GEMM, f16 out, optional K-split via grid.z ----------------
__global__ __launch_bounds__(256, 2) void gemm_h_kernel(
    const u16* __restrict__ A, const u16* __restrict__ B, u16* __restrict__ out,
    int ldk, int ksplit, int osplit, int N) {
    __shared__ u16 As[128 * 64];
    __shared__ u16 Bs[128 * 64];
    int z = blockIdx.z;
    int m0 = blockIdx.y * 128, n0 = blockIdx.x * 128;
    f32x4 acc[4][4];
    f32x4 zf = {0.f, 0.f, 0.f, 0.f};
#pragma unroll
    for (int i = 0; i < 4; i++)
#pragma unroll
        for (int j = 0; j < 4; j++) acc[i][j] = zf;
    gemm128_core(A, B, ldk, z * ksplit, (z + 1) * ksplit, m0, n0, As, Bs, acc);
    u16* o = out + (size_t)z * osplit;
    int lane = threadIdx.x & 63, w = threadIdx.x >> 6;
    int wm = (w >> 1) * 64, wn = (w & 1) * 64;
    int lrow = lane & 15, lg = lane >> 4;
#pragma unroll
    for (int i = 0; i < 4; i++)
#pragma unroll
        for (int j = 0; j < 4; j++)
#pragma unroll
            for (int r = 0; r < 4; r++) {
                int m = m0 + wm + i * 16 + lg * 4 + r;
                int n = n0 + wn + j * 16 + lrow;
                o[(size_t)m * N + n] = f2h(acc[i][j][r]);
            }
}

// ---------------- RoPE + L2 norm + sqk scale, f16 in-place ----------------
__global__ void qkprep_kernel(u16* __restrict__ qb, u16* __restrict__ kb,
                              const float* __restrict__ sqk) {
    u16* buf = blockIdx.z ? kb : qb;
    int pair = blockIdx.x * 4 + (threadIdx.x >> 6);  // (m,h) pair
    int m = pair >> 4, hh = pair & 15;
    int tt = m & 1023;  // t = m % T
    int d = threadIdx.x & 63;
    size_t off = (size_t)m * 1024 + hh * 64 + d;
    float x = h2f(buf[off]);
    float xn = __shfl_xor(x, 1);
    int j = (d & 1) ? ((d - 1) >> 1) : (32 + (d >> 1));
    float dv = exp2f(-(float)(j >> 1) * 0.41524101186092029f);  // log2(10000)/32
    float ang = (float)tt * dv;
    float e = (j & 1) ? cosf(ang) : sinf(ang);
    float xr = (d & 1) ? (xn * e) : (-xn * e);
    float ss = xr * xr;
#pragma unroll
    for (int o = 1; o < 64; o <<= 1) ss += __shfl_xor(ss, o);
    float sc = rsqrtf(ss) * sqk[hh * 64 + d] * 32.0f;
    buf[off] = f2h(xr * sc);
}

// ---------------- flash attention, split-KV x2, gate folded into softmax ----------------
// Q and K fragments read directly from global (L2-resident); only V^T + P in LDS.
// Partials: unnormalized y (f32) + (m, den) per q-row; merged by attn_merge_kernel.
__global__ __launch_bounds__(128) void attn_kernel(
    const u16* __restrict__ qb, const u16* __restrict__ kb, const u16* __restrict__ vb,
    const float* __restrict__ thr_c, const float* __restrict__ stp,
    float* __restrict__ yp, f32x2* __restrict__ mden) {
    const int T = 1024, C = 1024;
    int qt = 31 - (blockIdx.x >> 1);  // heavy-first
    int c = blockIdx.x & 1;           // kv chunk (strided tiles)
    int bh = blockIdx.y;
    int b = bh >> 4, hh = bh & 15;
    int q0 = qt * 32;
    int nkt = (q0 >> 6) + 1;
    __shared__ u16 Vt[64 * LDSS];  // transposed: Vt[d][kv]
    __shared__ u16 Ps[32 * LDSS];  // P[q_local][kv] (wave-private rows)
    int t = threadIdx.x;
    int lane = t & 63, w = t >> 6;
    int lrow = lane & 15, lg = lane >> 4, lk = lg * 8;

    // Q fragments straight from global
    const u16* qrowp = qb + (size_t)(b * T + q0 + w * 16 + lrow) * C + hh * 64;
    f16x8 qfr[2];
    qfr[0] = *reinterpret_cast<const f16x8*>(qrowp + lk);
    qfr[1] = *reinterpret_cast<const f16x8*>(qrowp + 32 + lk);

    float thr = thr_c[hh], st = stp[hh];
    float st8 = st * 8.0f, stthr = st * thr;
    float mrun = -1e30f, den = 0.f;
    f32x4 yacc[4];
    f32x4 zf = {0.f, 0.f, 0.f, 0.f};
#pragma unroll
    for (int i = 0; i < 4; i++) yacc[i] = zf;
    int qg = q0 + w * 16 + lrow;

    for (int kt = c; kt < nkt; kt += 2) {
        int kv0 = kt << 6;
        __syncthreads();  // protect Vt from previous iteration's readers
        {  // stage V transposed, paired b32 writes
            int kvp = t & 31, db = t >> 5;
            const u16* src = vb + (size_t)(b * T + kv0 + 2 * kvp) * C + hh * 64 + db * 16;
#pragma unroll
            for (int dd = 0; dd < 4; dd++) {
                u16x4 a = *reinterpret_cast<const u16x4*>(src + dd * 4);
                u16x4 bb = *reinterpret_cast<const u16x4*>(src + C + dd * 4);
#pragma unroll
                for (int e = 0; e < 4; e++) {
                    u32 v = (u32)a[e] | ((u32)bb[e] << 16);
                    *reinterpret_cast<u32*>(&Vt[(db * 16 + dd * 4 + e) * LDSS + 2 * kvp]) = v;
                }
            }
        }

        // K fragments straight from global; S^T = K . Q^T  (rows kv, cols q)
        f32x4 sacc[4];
#pragma unroll
        for (int f = 0; f < 4; f++) sacc[f] = zf;
#pragma unroll
        for (int ks = 0; ks < 2; ks++)
#pragma unroll
            for (int f = 0; f < 4; f++) {
                f16x8 kfr = *reinterpret_cast<const f16x8*>(
                    kb + (size_t)(b * T + kv0 + f * 16 + lrow) * C + hh * 64 + ks * 32 + lk);
                sacc[f] = mfma16(kfr, qfr[ks], sacc[f]);
            }
        __syncthreads();  // Vt staged (ds_writes also drained by this)

        float svv[16];
        float tmax = -1e30f;
        bool last = (kt == nkt - 1);
#pragma unroll
        for (int f = 0; f < 4; f++)
#pragma unroll
            for (int r = 0; r < 4; r++) {
                float sv = sacc[f][r];
                float s = sv * 8.0f;                   // * sqrt(D)
                float z = stthr - st8 * sv;            // -st*(s-thr)
                float l = __logf(1.0f + __expf(z));    // softplus(z), exact for z<=15
                float sp = s - ((z > 15.f) ? z : l);
                if (last) {
                    int kvg = kv0 + f * 16 + lg * 4 + r;
                    if (kvg > qg) sp = -1e30f;
                }
                svv[f * 4 + r] = sp;
                tmax = fmaxf(tmax, sp);
            }
        tmax = fmaxf(tmax, __shfl_xor(tmax, 16));
        tmax = fmaxf(tmax, __shfl_xor(tmax, 32));
        float mnew = fmaxf(mrun, tmax);
        float alpha = __expf(mrun - mnew);
        float tden = 0.f;
        u16 pu[16];
#pragma unroll
        for (int i = 0; i < 16; i++) {
            float p = __expf(svv[i] - mnew);
            u16 ph = f2h(p);
            pu[i] = ph;
            tden += h2f(ph);  // denominator from quantized P: rounding cancels
        }
        tden += __shfl_xor(tden, 16);
        tden += __shfl_xor(tden, 32);
        den = den * alpha + tden;
        mrun = mnew;

#pragma unroll
        for (int f = 0; f < 4; f++) {
            u16x4 u = {pu[f * 4 + 0], pu[f * 4 + 1], pu[f * 4 + 2], pu[f * 4 + 3]};
            *reinterpret_cast<u16x4*>(&Ps[(w * 16 + lrow) * LDSS + f * 16 + lg * 4]) = u;
        }
        float a4[4];
#pragma unroll
        for (int r = 0; r < 4; r++) a4[r] = __shfl(alpha, lg * 4 + r);
#pragma unroll
        for (int nf = 0; nf < 4; nf++)
#pragma unroll
            for (int r = 0; r < 4; r++) yacc[nf][r] *= a4[r];

        // PV (P rows wave-private; lgkmcnt orders ds write->read)
#pragma unroll
        for (int ks = 0; ks < 2; ks++) {
            f16x8 pf = *reinterpret_cast<f16x8*>(&Ps[(w * 16 + lrow) * LDSS + ks * 32 + lk]);
#pragma unroll
            for (int nf = 0; nf < 4; nf++) {
                f16x8 vf = *reinterpret_cast<f16x8*>(&Vt[(nf * 16 + lrow) * LDSS + ks * 32 + lk]);
                yacc[nf] = mfma16(pf, vf, yacc[nf]);
            }
        }
    }
    // store partials: unnormalized y (f32) + (m, den)
    float* ypc = yp + (size_t)c * 2097152;
#pragma unroll
    for (int nf = 0; nf < 4; nf++)
#pragma unroll
        for (int r = 0; r < 4; r++) {
            int qrow = q0 + w * 16 + lg * 4 + r;
            ypc[(size_t)(b * T + qrow) * C + hh * 64 + nf * 16 + lrow] = yacc[nf][r];
        }
    if (lg == 0) {
        f32x2 md;
        md[0] = mrun; md[1] = den;
        mden[((size_t)c * 32 + bh) * 1024 + (q0 + w * 16 + lrow)] = md;
    }
}

// ---------------- merge split-KV partials -> normalized f16 y ----------------
__global__ void attn_merge_kernel(const float* __restrict__ yp, const f32x2* __restrict__ mden,
                                  u16* __restrict__ y) {
    int row = blockIdx.x;  // b*T + t
    int b = row >> 10, tr = row & 1023;
    int t = threadIdx.x;
#pragma unroll
    for (int i = 0; i < 4; i++) {
        int idx = t + 256 * i;
        int hh = idx >> 6;
        f32x2 md0 = mden[((size_t)0 * 32 + b * 16 + hh) * 1024 + tr];
        f32x2 md1 = mden[((size_t)1 * 32 + b * 16 + hh) * 1024 + tr];
        float M = fmaxf(md0[0], md1[0]);
        float w0 = __expf(md0[0] - M), w1 = __expf(md1[0] - M);
        float dn = md0[1] * w0 + md1[1] * w1;
        size_t off = (size_t)row * 1024 + idx;
        float v = (yp[off] * w0 + yp[off + 2097152] * w1) / dn;
        y[off] = f2h(v);
    }
}

// ---------------- FC (u and v halves) + SiLU gate fused, 128x128 tile ----------------
__global__ __launch_bounds__(256, 2) void fc_silu_kernel(
    const u16* __restrict__ h1h, const u16* __restrict__ Wfch,
    const float* __restrict__ suv, u16* __restrict__ xmlp) {
    __shared__ u16 As[128 * 64];
    __shared__ u16 Bu[128 * 64];
    __shared__ u16 Bv[128 * 64];
    int m0 = blockIdx.y * 128, n0 = blockIdx.x * 128;
    f32x4 au[4][4], av[4][4];
    f32x4 zf = {0.f, 0.f, 0.f, 0.f};
#pragma unroll
    for (int i = 0; i < 4; i++)
#pragma unroll
        for (int j = 0; j < 4; j++) { au[i][j] = zf; av[i][j] = zf; }
    int lane = threadIdx.x & 63, w = threadIdx.x >> 6;
    int wm = (w >> 1) * 64, wn = (w & 1) * 64;
    int lrow = lane & 15, lg = lane >> 4;
    for (int k0 = 0; k0 < 1024; k0 += 64) {
        __syncthreads();
        stage128(h1h, m0, 1024, k0, As);
        stage128(Wfch, n0, 1024, k0, Bu);
        stage128(Wfch, 4096 + n0, 1024, k0, Bv);
        __syncthreads();
#pragma unroll
        for (int ks = 0; ks < 2; ks++) {
            f16x8 af[4], bu[4], bv[4];
#pragma unroll
            for (int i = 0; i < 4; i++) {
                af[i] = *reinterpret_cast<f16x8*>(&As[(wm + i * 16 + lrow) * 64 + ks * 32 + lg * 8]);
                bu[i] = *reinterpret_cast<f16x8*>(&Bu[(wn + i * 16 + lrow) * 64 + ks * 32 + lg * 8]);
                bv[i] = *reinterpret_cast<f16x8*>(&Bv[(wn + i * 16 + lrow) * 64 + ks * 32 + lg * 8]);
            }
#pragma unroll
            for (int i = 0; i < 4; i++)
#pragma unroll
                for (int j = 0; j < 4; j++) {
                    au[i][j] = mfma16(af[i], bu[j], au[i][j]);
                    av[i][j] = mfma16(af[i], bv[j], av[i][j]);
                }
        }
    }
#pragma unroll
    for (int i = 0; i < 4; i++)
#pragma unroll
        for (int j = 0; j < 4; j++) {
            int n = n0 + wn + j * 16 + lrow;
            float su = suv[n] * 32.0f;
            float sv = suv[4096 + n] * 32.0f;
#pragma unroll
            for (int r = 0; r < 4; r++) {
                int m = m0 + wm + i * 16 + lg * 4 + r;
                float uu = au[i][j][r] * su;
                float vv = av[i][j][r] * sv;
                float sig = 1.0f / (1.0f + __expf(-vv));
                xmlp[(size_t)m * 4096 + n] = f2h(uu * vv * sig);
            }
        }
}

// ---------------- justnorm residual-lerp-justnorm; delta = sum of f16 parts ----------------
__global__ void normres_kernel(const float* __restrict__ base, const u16* __restrict__ dparts,
                               int nparts, int pstride, const float* __restrict__ alpha,
                               float* __restrict__ outf, u16* __restrict__ outh) {
    int row = blockIdx.x;
    int t = threadIdx.x;
    const float* pb = base + (size_t)row * 1024;
    float xb[4], xd[4];
    float ssb = 0.f, ssd = 0.f;
#pragma unroll
    for (int i = 0; i < 4; i++) {
        size_t off = (size_t)row * 1024 + t + 256 * i;
        xb[i] = pb[t + 256 * i];
        float d = 0.f;
        for (int p = 0; p < nparts; p++) d += h2f(dparts[off + (size_t)p * pstride]);
        xd[i] = d;
        ssb += xb[i] * xb[i];
        ssd += xd[i] * xd[i];
    }
#pragma unroll
    for (int o = 1; o < 64; o <<= 1) { ssb += __shfl_xor(ssb, o); ssd += __shfl_xor(ssd, o); }
    __shared__ float red[8];
    int w = t >> 6;
    if ((t & 63) == 0) { red[w * 2] = ssb; red[w * 2 + 1] = ssd; }
    __syncthreads();
    ssb = red[0] + red[2] + red[4] + red[6];
    ssd = red[1] + red[3] + red[5] + red[7];
    float rb = rsqrtf(ssb), rd = rsqrtf(ssd);
    float c[4];
    float ssc = 0.f;
#pragma unroll
    for (int i = 0; i < 4; i++) {
        float a = xb[i] * rb;
        float bb = xd[i] * rd;
        float lr = fabsf(alpha[t + 256 * i] * 1.6f);  // 0.05/0.03125
        float cv = a + lr * (bb - a);
        c[i] = cv;
        ssc += cv * cv;
    }
#pragma unroll
    for (int o = 1; o < 64; o <<= 1) ssc += __shfl_xor(ssc, o);
    __syncthreads();
    if ((t & 63) == 0) red[w] = ssc;
    __syncthreads();
    ssc = red[0] + red[1] + red[2] + red[3];
    float rc = rsqrtf(ssc);
#pragma unroll
    for (int i = 0; i < 4; i++) {
        float v = c[i] * rc;
        size_t off = (size_t)row * 1024 + t + 256 * i;
        outf[off] = v;
        if (outh) outh[off] = f2h(v);
    }
}

extern "C" void kernel_launch(void* const* d_in, const int* in_sizes, int n_in,
                              void* d_out, int out_size, void* d_ws, size_t ws_size,
                              hipStream_t stream) {
    const float* h = (const float*)d_in[0];
    const float* Wq = (const float*)d_in[1];
    const float* Wk = (const float*)d_in[2];
    const float* Wv = (const float*)d_in[3];
    const float* Wo = (const float*)d_in[4];
    const float* Wfc = (const float*)d_in[5];
    const float* Wproj = (const float*)d_in[6];
    const float* sqk = (const float*)d_in[7];
    const float* suv = (const float*)d_in[8];
    const float* attn_alpha = (const float*)d_in[9];
    const float* mlp_alpha = (const float*)d_in[10];
    const float* thr_c = (const float*)d_in[11];
    const float* stp = (const float*)d_in[12];

    char* ws = (char*)d_ws;
    u16* f16heap = (u16*)ws;
    u16* hb     = f16heap + 0;         // 2048x1024       ( 0..4MB)
    u16* Wqh    = f16heap + 2097152;   // 1024x1024       ( 4..6MB)
    u16* Wkh    = f16heap + 3145728;   //                 ( 6..8MB)
    u16* Wvh    = f16heap + 4194304;   //                 ( 8..10MB)
    u16* Woh    = f16heap + 5242880;   //                 (10..12MB)
    u16* Wprojh = f16heap + 6291456;   // 1024x4096       (12..20MB)
    u16* Wfch   = f16heap + 10485760;  // 8192x1024       (20..36MB; reused as proj partials)
    u16* partsP = Wfch;                // 4 x (2048x1024) proj partials
    u16* qb   = (u16*)(ws + (size_t)36 * MB);
    u16* kb   = (u16*)(ws + (size_t)40 * MB);
    u16* vb   = (u16*)(ws + (size_t)44 * MB);
    u16* y    = (u16*)(ws + (size_t)48 * MB);
    float* yp = (float*)(ws + (size_t)52 * MB);   // 2 x 8MB f32 attn partials (52..68; dead after merge)
    u16* hattP = qb;                   // 2 x (2048x1024) Wo partials (qb/kb region, free post-attn)
    float* h1 = (float*)(ws + (size_t)56 * MB);   // written after yp consumed
    u16* h1h  = (u16*)(ws + (size_t)64 * MB);
    f32x2* mden = (f32x2*)(ws + (size_t)68 * MB); // 512KB (68..68.5)
    u16* xmlp = (u16*)(ws + (size_t)36 * MB);  // alias over qb..y (consumed)
    float* out = (float*)d_out;

    cvt_kernel<<<9216, 256, 0, stream>>>(h, Wq, Wk, Wv, Wo, Wfc, Wproj, f16heap);
    qkv_h_kernel<<<dim3(8, 16, 3), 256, 0, stream>>>(hb, Wqh, Wkh, Wvh, qb, kb, vb);
    qkprep_kernel<<<dim3(8192, 1, 2), 256, 0, stream>>>(qb, kb, sqk);
    attn_kernel<<<dim3(64, 32), 128, 0, stream>>>(qb, kb, vb, thr_c, stp, yp, mden);
    attn_merge_kernel<<<2048, 256, 0, stream>>>(yp, mden, y);
    gemm_h_kernel<<<dim3(8, 16, 2), 256, 0, stream>>>(y, Woh, hattP, 1024, 512, 2097152, 1024);
    normres_kernel<<<2048, 256, 0, stream>>>(h, hattP, 2, 2097152, attn_alpha, h1, h1h);
    fc_silu_kernel<<<dim3(32, 16), 256, 0, stream>>>(h1h, Wfch, suv, xmlp);
    gemm_h_kernel<<<dim3(8, 16, 4), 256, 0, stream>>>(xmlp, Wprojh, partsP, 4096, 1024, 2097152, 1024);
    normres_kernel<<<2048, 256, 0, stream>>>(h1, partsP, 4, 2097152, mlp_alpha, out, (u16*)nullptr);
}

// Round 6
// 205.894 us; speedup vs baseline: 2.3210x; 1.0197x over previous
//
#include <hip/hip_runtime.h>
#include <hip/hip_bf16.h>
#include <math.h>

typedef _Float16 f16x8 __attribute__((ext_vector_type(8)));
typedef float f32x4 __attribute__((ext_vector_type(4)));
typedef float f32x2 __attribute__((ext_vector_type(2)));
typedef unsigned short u16;
typedef unsigned int u32;
typedef u16 u16x4 __attribute__((ext_vector_type(4)));
typedef u16 u16x8 __attribute__((ext_vector_type(8)));

#define DEVI static __device__ __forceinline__
#define LDSS 72  // attn LDS row stride (16B-aligned pad: conflict-light)
#define MB (1u << 20)

DEVI u16 f2h(float f) {
    _Float16 h = (_Float16)f;
    return __builtin_bit_cast(u16, h);
}
DEVI float h2f(u16 u) {
    return (float)__builtin_bit_cast(_Float16, u);
}
DEVI f32x4 mfma16(f16x8 a, f16x8 b, f32x4 c) {
    return __builtin_amdgcn_mfma_f32_16x16x32_f16(a, b, c, 0, 0, 0);
}
DEVI void gload16(const u16* g, u16* l) {
    __builtin_amdgcn_global_load_lds((const __attribute__((address_space(1))) void*)g,
                                     (__attribute__((address_space(3))) void*)l, 16, 0, 0);
}

// stage a 128x64 f16 tile global -> LDS (linear [128][64]) via global_load_lds.
DEVI void stage128(const u16* __restrict__ g, size_t row0, int ldg, int k0, u16* lds) {
    int t = threadIdx.x;
    const u16* src = g + (row0 + (size_t)(t >> 3)) * (size_t)ldg + k0 + (t & 7) * 8;
    u16* dst = lds + (t >> 6) * 512;  // wave-uniform
#pragma unroll
    for (int is = 0; is < 4; is++)
        gload16(src + (size_t)is * 32 * ldg, dst + is * 2048);
}

// ---------------- 128x128 MFMA core: C[m,n] = sum_k A[m,k]*B[n,k], f16 in ----------------
DEVI void gemm128_core(const u16* __restrict__ A, const u16* __restrict__ B,
                       int ldk, int kbeg, int kend, int m0, int n0,
                       u16* As, u16* Bs, f32x4 acc[4][4]) {
    int lane = threadIdx.x & 63, w = threadIdx.x >> 6;
    int wm = (w >> 1) * 64, wn = (w & 1) * 64;
    int lrow = lane & 15, lg = lane >> 4;
    for (int k0 = kbeg; k0 < kend; k0 += 64) {
        __syncthreads();
        stage128(A, m0, ldk, k0, As);
        stage128(B, n0, ldk, k0, Bs);
        __syncthreads();
#pragma unroll
        for (int ks = 0; ks < 2; ks++) {
            f16x8 af[4], bf[4];
#pragma unroll
            for (int i = 0; i < 4; i++) {
                af[i] = *reinterpret_cast<f16x8*>(&As[(wm + i * 16 + lrow) * 64 + ks * 32 + lg * 8]);
                bf[i] = *reinterpret_cast<f16x8*>(&Bs[(wn + i * 16 + lrow) * 64 + ks * 32 + lg * 8]);
            }
#pragma unroll
            for (int i = 0; i < 4; i++)
#pragma unroll
                for (int j = 0; j < 4; j++)
                    acc[i][j] = mfma16(af[i], bf[j], acc[i][j]);
        }
    }
}

// ---------------- fp32 -> f16 one-time conversion of h + all weights ----------------
__global__ void cvt_kernel(const float* __restrict__ h, const float* __restrict__ Wq,
                           const float* __restrict__ Wk, const float* __restrict__ Wv,
                           const float* __restrict__ Wo, const float* __restrict__ Wfc,
                           const float* __restrict__ Wproj, u16* __restrict__ dst) {
    int bid = blockIdx.x;
    const float* src;
    size_t doff;
    int sb;
    if (bid < 1024)      { src = h;     sb = 0;    doff = 0; }
    else if (bid < 1536) { src = Wq;    sb = 1024; doff = 2097152; }
    else if (bid < 2048) { src = Wk;    sb = 1536; doff = 3145728; }
    else if (bid < 2560) { src = Wv;    sb = 2048; doff = 4194304; }
    else if (bid < 3072) { src = Wo;    sb = 2560; doff = 5242880; }
    else if (bid < 7168) { src = Wfc;   sb = 3072; doff = 10485760; }
    else                 { src = Wproj; sb = 7168; doff = 6291456; }
    size_t idx = (size_t)(bid - sb) * 2048 + threadIdx.x * 8;
    f32x4 a = *reinterpret_cast<const f32x4*>(src + idx);
    f32x4 b = *reinterpret_cast<const f32x4*>(src + idx + 4);
    u16x8 o;
    o[0] = f2h(a[0]); o[1] = f2h(a[1]); o[2] = f2h(a[2]); o[3] = f2h(a[3]);
    o[4] = f2h(b[0]); o[5] = f2h(b[1]); o[6] = f2h(b[2]); o[7] = f2h(b[3]);
    *reinterpret_cast<u16x8*>(dst + doff + idx) = o;
}

// ---------------- QKV ----------------
__global__ __launch_bounds__(256, 2) void qkv_h_kernel(
    const u16* __restrict__ hb, const u16* __restrict__ Wqh, const u16* __restrict__ Wkh,
    const u16* __restrict__ Wvh, u16* __restrict__ qb, u16* __restrict__ kb, u16* __restrict__ vb) {
    __shared__ u16 As[128 * 64];
    __shared__ u16 Bs[128 * 64];
    int z = blockIdx.z;
    const u16* W = (z == 0) ? Wqh : (z == 1) ? Wkh : Wvh;
    u16* dst = (z == 0) ? qb : (z == 1) ? kb : vb;
    int m0 = blockIdx.y * 128, n0 = blockIdx.x * 128;
    f32x4 acc[4][4];
    f32x4 zf = {0.f, 0.f, 0.f, 0.f};
#pragma unroll
    for (int i = 0; i < 4; i++)
#pragma unroll
        for (int j = 0; j < 4; j++) acc[i][j] = zf;
    gemm128_core(hb, W, 1024, 0, 1024, m0, n0, As, Bs, acc);
    int lane = threadIdx.x & 63, w = threadIdx.x >> 6;
    int wm = (w >> 1) * 64, wn = (w & 1) * 64;
    int lrow = lane & 15, lg = lane >> 4;
#pragma unroll
    for (int i = 0; i < 4; i++)
#pragma unroll
        for (int j = 0; j < 4; j++)
#pragma unroll
            for (int r = 0; r < 4; r++) {
                int m = m0 + wm + i * 16 + lg * 4 + r;
                int n = n0 + wn + j * 16 + lrow;
                dst[(size_t)m * 1024 + n] = f2h(acc[i][j][r]);
            }
}

// ---------------- generic 128x128 GEMM, f16 out, optional K-split via grid.z ----------------
__global__ __launch_bounds__(256, 2) void gemm_h_kernel(
    const u16* __restrict__ A, const u16* __restrict__ B, u16* __restrict__ out,
    int ldk, int ksplit, int osplit, int N) {
    __shared__ u16 As[128 * 64];
    __shared__ u16 Bs[128 * 64];
    int z = blockIdx.z;
    int m0 = blockIdx.y * 128, n0 = blockIdx.x * 128;
    f32x4 acc[4][4];
    f32x4 zf = {0.f, 0.f, 0.f, 0.f};
#pragma unroll
    for (int i = 0; i < 4; i++)
#pragma unroll
        for (int j = 0; j < 4; j++) acc[i][j] = zf;
    gemm128_core(A, B, ldk, z * ksplit, (z + 1) * ksplit, m0, n0, As, Bs, acc);
    u16* o = out + (size_t)z * osplit;
    int lane = threadIdx.x & 63, w = threadIdx.x >> 6;
    int wm = (w >> 1) * 64, wn = (w & 1) * 64;
    int lrow = lane & 15, lg = lane >> 4;
#pragma unroll
    for (int i = 0; i < 4; i++)
#pragma unroll
        for (int j = 0; j < 4; j++)
#pragma unroll
            for (int r = 0; r < 4; r++) {
                int m = m0 + wm + i * 16 + lg * 4 + r;
                int n = n0 + wn + j * 16 + lrow;
                o[(size_t)m * N + n] = f2h(acc[i][j][r]);
            }
}

// ---------------- RoPE + L2 norm + sqk scale, f16 in-place ----------------
__global__ void qkprep_kernel(u16* __restrict__ qb, u16* __restrict__ kb,
                              const float* __restrict__ sqk) {
    u16* buf = blockIdx.z ? kb : qb;
    int pair = blockIdx.x * 4 + (threadIdx.x >> 6);  // (m,h) pair
    int m = pair >> 4, hh = pair & 15;
    int tt = m & 1023;  // t = m % T
    int d = threadIdx.x & 63;
    size_t off = (size_t)m * 1024 + hh * 64 + d;
    float x = h2f(buf[off]);
    float xn = __shfl_xor(x, 1);
    int j = (d & 1) ? ((d - 1) >> 1) : (32 + (d >> 1));
    float dv = exp2f(-(float)(j >> 1) * 0.41524101186092029f);  // log2(10000)/32
    float ang = (float)tt * dv;
    float e = (j & 1) ? cosf(ang) : sinf(ang);
    float xr = (d & 1) ? (xn * e) : (-xn * e);
    float ss = xr * xr;
#pragma unroll
    for (int o = 1; o < 64; o <<= 1) ss += __shfl_xor(ss, o);
    float sc = rsqrtf(ss) * sqk[hh * 64 + d] * 32.0f;
    buf[off] = f2h(xr * sc);
}

// ---------------- flash attention, split-KV x2, gate folded into softmax ----------------
// Pipelined: K-frag + V-reg prefetch for tile kt+2 issued during tile kt's compute;
// Vt double-buffered -> ONE barrier per tile. Branch-free softmax:
// p = exp(s - m) * rcp(1 + exp(st*(thr-s))); m = max(s) - softplus(st*(thr - max s))
// (valid: s - softplus(st*(thr-s)) is monotone increasing in s).
__global__ __launch_bounds__(128) void attn_kernel(
    const u16* __restrict__ qb, const u16* __restrict__ kb, const u16* __restrict__ vb,
    const float* __restrict__ thr_c, const float* __restrict__ stp,
    float* __restrict__ yp, f32x2* __restrict__ mden) {
    const int T = 1024, C = 1024;
    int qt = 31 - (blockIdx.x >> 1);  // heavy-first
    int c = blockIdx.x & 1;           // kv chunk (strided tiles)
    int bh = blockIdx.y;
    int b = bh >> 4, hh = bh & 15;
    int q0 = qt * 32;
    int nkt = (q0 >> 6) + 1;
    __shared__ u16 Vt[2][64 * LDSS];  // double-buffered transposed V
    __shared__ u16 Ps[32 * LDSS];     // P[q_local][kv] (wave-private rows)
    int t = threadIdx.x;
    int lane = t & 63, w = t >> 6;
    int lrow = lane & 15, lg = lane >> 4, lk = lg * 8;
    int kvp = t & 31, db = t >> 5;    // V-stage lane mapping

    // Q fragments straight from global (L2-resident)
    const u16* qrowp = qb + (size_t)(b * T + q0 + w * 16 + lrow) * C + hh * 64;
    f16x8 qfr[2];
    qfr[0] = *reinterpret_cast<const f16x8*>(qrowp + lk);
    qfr[1] = *reinterpret_cast<const f16x8*>(qrowp + 32 + lk);

    float thr = thr_c[hh], st = stp[hh];
    float stthr = st * thr;
    float mrun = -1e30f, den = 0.f;
    f32x4 yacc[4];
    f32x4 zf = {0.f, 0.f, 0.f, 0.f};
#pragma unroll
    for (int i = 0; i < 4; i++) yacc[i] = zf;
    int qg = q0 + w * 16 + lrow;

    f16x8 kpre[8];   // prefetched K fragments
    u16x4 vr[8];     // prefetched V rows (2 kv rows x 16 d)
    const u16* kbase0 = kb + (size_t)(b * T + lrow) * C + hh * 64 + lk;
    const u16* vbase0 = vb + (size_t)(b * T + 2 * kvp) * C + hh * 64 + db * 16;

    if (c < nkt) {  // prologue prefetch of tile c
        const u16* kbase = kbase0 + (size_t)(c << 6) * C;
        const u16* vsrc = vbase0 + (size_t)(c << 6) * C;
#pragma unroll
        for (int ks = 0; ks < 2; ks++)
#pragma unroll
            for (int f = 0; f < 4; f++)
                kpre[ks * 4 + f] = *reinterpret_cast<const f16x8*>(kbase + (size_t)(f * 16) * C + ks * 32);
#pragma unroll
        for (int dd = 0; dd < 4; dd++) {
            vr[dd * 2] = *reinterpret_cast<const u16x4*>(vsrc + dd * 4);
            vr[dd * 2 + 1] = *reinterpret_cast<const u16x4*>(vsrc + C + dd * 4);
        }
    }

    for (int kt = c; kt < nkt; kt += 2) {
        int kv0 = kt << 6;
        u16* VB = Vt[(kt >> 1) & 1];
        // store prefetched V (transposed) into this tile's buffer
#pragma unroll
        for (int dd = 0; dd < 4; dd++)
#pragma unroll
            for (int e = 0; e < 4; e++) {
                u32 v = (u32)vr[dd * 2][e] | ((u32)vr[dd * 2 + 1][e] << 16);
                *reinterpret_cast<u32*>(&VB[(db * 16 + dd * 4 + e) * LDSS + 2 * kvp]) = v;
            }
        // S^T = K . Q^T from prefetched K fragments
        f32x4 sacc[4];
#pragma unroll
        for (int f = 0; f < 4; f++) sacc[f] = zf;
#pragma unroll
        for (int ks = 0; ks < 2; ks++)
#pragma unroll
            for (int f = 0; f < 4; f++)
                sacc[f] = mfma16(kpre[ks * 4 + f], qfr[ks], sacc[f]);

        // prefetch tile kt+2 (latency hidden under softmax+PV)
        if (kt + 2 < nkt) {
            const u16* kbase = kbase0 + (size_t)((kt + 2) << 6) * C;
            const u16* vsrc = vbase0 + (size_t)((kt + 2) << 6) * C;
#pragma unroll
            for (int ks = 0; ks < 2; ks++)
#pragma unroll
                for (int f = 0; f < 4; f++)
                    kpre[ks * 4 + f] = *reinterpret_cast<const f16x8*>(kbase + (size_t)(f * 16) * C + ks * 32);
#pragma unroll
            for (int dd = 0; dd < 4; dd++) {
                vr[dd * 2] = *reinterpret_cast<const u16x4*>(vsrc + dd * 4);
                vr[dd * 2 + 1] = *reinterpret_cast<const u16x4*>(vsrc + C + dd * 4);
            }
        }

        // ----- softmax (branch-free) -----
        float svv[16];
        float tmax = -1e30f;
        bool last = (kt == nkt - 1);
#pragma unroll
        for (int f = 0; f < 4; f++)
#pragma unroll
            for (int r = 0; r < 4; r++) {
                float s = sacc[f][r] * 8.0f;  // * sqrt(D)
                if (last) {
                    int kvg = kv0 + f * 16 + lg * 4 + r;
                    if (kvg > qg) s = -1e30f;
                }
                svv[f * 4 + r] = s;
                tmax = fmaxf(tmax, s);
            }
        tmax = fmaxf(tmax, __shfl_xor(tmax, 16));
        tmax = fmaxf(tmax, __shfl_xor(tmax, 32));
        // row max of gated score via monotonicity (single softplus)
        float zM = stthr - st * tmax;
        float spM = tmax - __logf(1.0f + __expf(zM));
        float mnew = fmaxf(mrun, spM);
        float alpha = __expf(mrun - mnew);
        float tden = 0.f;
        u16 pu[16];
#pragma unroll
        for (int i = 0; i < 16; i++) {
            float s = svv[i];
            float e2 = __expf(s - mnew);
            float eg = __expf(stthr - st * s);
            float p = e2 * __builtin_amdgcn_rcpf(1.0f + eg);
            u16 ph = f2h(p);
            pu[i] = ph;
            tden += h2f(ph);  // denominator from quantized P: rounding cancels
        }
        tden += __shfl_xor(tden, 16);
        tden += __shfl_xor(tden, 32);
        den = den * alpha + tden;
        mrun = mnew;

#pragma unroll
        for (int f = 0; f < 4; f++) {
            u16x4 u = {pu[f * 4 + 0], pu[f * 4 + 1], pu[f * 4 + 2], pu[f * 4 + 3]};
            *reinterpret_cast<u16x4*>(&Ps[(w * 16 + lrow) * LDSS + f * 16 + lg * 4]) = u;
        }
        float a4[4];
#pragma unroll
        for (int r = 0; r < 4; r++) a4[r] = __shfl(alpha, lg * 4 + r);
#pragma unroll
        for (int nf = 0; nf < 4; nf++)
#pragma unroll
            for (int r = 0; r < 4; r++) yacc[nf][r] *= a4[r];

        __syncthreads();  // VB staged; single barrier per tile (dbuf removes WAR hazard)

        // PV (P rows wave-private; lgkmcnt orders ds write->read)
#pragma unroll
        for (int ks = 0; ks < 2; ks++) {
            f16x8 pf = *reinterpret_cast<f16x8*>(&Ps[(w * 16 + lrow) * LDSS + ks * 32 + lk]);
#pragma unroll
            for (int nf = 0; nf < 4; nf++) {
                f16x8 vf = *reinterpret_cast<f16x8*>(&VB[(nf * 16 + lrow) * LDSS + ks * 32 + lk]);
                yacc[nf] = mfma16(pf, vf, yacc[nf]);
            }
        }
    }
    // store partials: unnormalized y (f32) + (m, den)
    float* ypc = yp + (size_t)c * 2097152;
#pragma unroll
    for (int nf = 0; nf < 4; nf++)
#pragma unroll
        for (int r = 0; r < 4; r++) {
            int qrow = q0 + w * 16 + lg * 4 + r;
            ypc[(size_t)(b * T + qrow) * C + hh * 64 + nf * 16 + lrow] = yacc[nf][r];
        }
    if (lg == 0) {
        f32x2 md;
        md[0] = mrun; md[1] = den;
        mden[((size_t)c * 32 + bh) * 1024 + (q0 + w * 16 + lrow)] = md;
    }
}

// ---------------- merge split-KV partials -> normalized f16 y ----------------
__global__ void attn_merge_kernel(const float* __restrict__ yp, const f32x2* __restrict__ mden,
                                  u16* __restrict__ y) {
    int row = blockIdx.x;  // b*T + t
    int b = row >> 10, tr = row & 1023;
    int t = threadIdx.x;
#pragma unroll
    for (int i = 0; i < 4; i++) {
        int idx = t + 256 * i;
        int hh = idx >> 6;
        f32x2 md0 = mden[((size_t)0 * 32 + b * 16 + hh) * 1024 + tr];
        f32x2 md1 = mden[((size_t)1 * 32 + b * 16 + hh) * 1024 + tr];
        float M = fmaxf(md0[0], md1[0]);
        float w0 = __expf(md0[0] - M), w1 = __expf(md1[0] - M);
        float dn = md0[1] * w0 + md1[1] * w1;
        size_t off = (size_t)row * 1024 + idx;
        float v = (yp[off] * w0 + yp[off + 2097152] * w1) / dn;
        y[off] = f2h(v);
    }
}

// ---------------- FC (u and v halves) + SiLU gate fused, 128x128 tile ----------------
__global__ __launch_bounds__(256, 2) void fc_silu_kernel(
    const u16* __restrict__ h1h, const u16* __restrict__ Wfch,
    const float* __restrict__ suv, u16* __restrict__ xmlp) {
    __shared__ u16 As[128 * 64];
    __shared__ u16 Bu[128 * 64];
    __shared__ u16 Bv[128 * 64];
    int m0 = blockIdx.y * 128, n0 = blockIdx.x * 128;
    f32x4 au[4][4], av[4][4];
    f32x4 zf = {0.f, 0.f, 0.f, 0.f};
#pragma unroll
    for (int i = 0; i < 4; i++)
#pragma unroll
        for (int j = 0; j < 4; j++) { au[i][j] = zf; av[i][j] = zf; }
    int lane = threadIdx.x & 63, w = threadIdx.x >> 6;
    int wm = (w >> 1) * 64, wn = (w & 1) * 64;
    int lrow = lane & 15, lg = lane >> 4;
    for (int k0 = 0; k0 < 1024; k0 += 64) {
        __syncthreads();
        stage128(h1h, m0, 1024, k0, As);
        stage128(Wfch, n0, 1024, k0, Bu);
        stage128(Wfch, 4096 + n0, 1024, k0, Bv);
        __syncthreads();
#pragma unroll
        for (int ks = 0; ks < 2; ks++) {
            f16x8 af[4], bu[4], bv[4];
#pragma unroll
            for (int i = 0; i < 4; i++) {
                af[i] = *reinterpret_cast<f16x8*>(&As[(wm + i * 16 + lrow) * 64 + ks * 32 + lg * 8]);
                bu[i] = *reinterpret_cast<f16x8*>(&Bu[(wn + i * 16 + lrow) * 64 + ks * 32 + lg * 8]);
                bv[i] = *reinterpret_cast<f16x8*>(&Bv[(wn + i * 16 + lrow) * 64 + ks * 32 + lg * 8]);
            }
#pragma unroll
            for (int i = 0; i < 4; i++)
#pragma unroll
                for (int j = 0; j < 4; j++) {
                    au[i][j] = mfma16(af[i], bu[j], au[i][j]);
                    av[i][j] = mfma16(af[i], bv[j], av[i][j]);
                }
        }
    }
#pragma unroll
    for (int i = 0; i < 4; i++)
#pragma unroll
        for (int j = 0; j < 4; j++) {
            int n = n0 + wn + j * 16 + lrow;
            float su = suv[n] * 32.0f;
            float sv = suv[4096 + n] * 32.0f;
#pragma unroll
            for (int r = 0; r < 4; r++) {
                int m = m0 + wm + i * 16 + lg * 4 + r;
                float uu = au[i][j][r] * su;
                float vv = av[i][j][r] * sv;
                float sig = 1.0f / (1.0f + __expf(-vv));
                xmlp[(size_t)m * 4096 + n] = f2h(uu * vv * sig);
            }
        }
}

// ---------------- justnorm residual-lerp-justnorm; delta = sum of f16 parts ----------------
__global__ void normres_kernel(const float* __restrict__ base, const u16* __restrict__ dparts,
                               int nparts, int pstride, const float* __restrict__ alpha,
                               float* __restrict__ outf, u16* __restrict__ outh) {
    int row = blockIdx.x;
    int t = threadIdx.x;
    const float* pb = base + (size_t)row * 1024;
    float xb[4], xd[4];
    float ssb = 0.f, ssd = 0.f;
#pragma unroll
    for (int i = 0; i < 4; i++) {
        size_t off = (size_t)row * 1024 + t + 256 * i;
        xb[i] = pb[t + 256 * i];
        float d = 0.f;
        for (int p = 0; p < nparts; p++) d += h2f(dparts[off + (size_t)p * pstride]);
        xd[i] = d;
        ssb += xb[i] * xb[i];
        ssd += xd[i] * xd[i];
    }
#pragma unroll
    for (int o = 1; o < 64; o <<= 1) { ssb += __shfl_xor(ssb, o); ssd += __shfl_xor(ssd, o); }
    __shared__ float red[8];
    int w = t >> 6;
    if ((t & 63) == 0) { red[w * 2] = ssb; red[w * 2 + 1] = ssd; }
    __syncthreads();
    ssb = red[0] + red[2] + red[4] + red[6];
    ssd = red[1] + red[3] + red[5] + red[7];
    float rb = rsqrtf(ssb), rd = rsqrtf(ssd);
    float c[4];
    float ssc = 0.f;
#pragma unroll
    for (int i = 0; i < 4; i++) {
        float a = xb[i] * rb;
        float bb = xd[i] * rd;
        float lr = fabsf(alpha[t + 256 * i] * 1.6f);  // 0.05/0.03125
        float cv = a + lr * (bb - a);
        c[i] = cv;
        ssc += cv * cv;
    }
#pragma unroll
    for (int o = 1; o < 64; o <<= 1) ssc += __shfl_xor(ssc, o);
    __syncthreads();
    if ((t & 63) == 0) red[w] = ssc;
    __syncthreads();
    ssc = red[0] + red[1] + red[2] + red[3];
    float rc = rsqrtf(ssc);
#pragma unroll
    for (int i = 0; i < 4; i++) {
        float v = c[i] * rc;
        size_t off = (size_t)row * 1024 + t + 256 * i;
        outf[off] = v;
        if (outh) outh[off] = f2h(v);
    }
}

extern "C" void kernel_launch(void* const* d_in, const int* in_sizes, int n_in,
                              void* d_out, int out_size, void* d_ws, size_t ws_size,
                              hipStream_t stream) {
    const float* h = (const float*)d_in[0];
    const float* Wq = (const float*)d_in[1];
    const float* Wk = (const float*)d_in[2];
    const float* Wv = (const float*)d_in[3];
    const float* Wo = (const float*)d_in[4];
    const float* Wfc = (const float*)d_in[5];
    const float* Wproj = (const float*)d_in[6];
    const float* sqk = (const float*)d_in[7];
    const float* suv = (const float*)d_in[8];
    const float* attn_alpha = (const float*)d_in[9];
    const float* mlp_alpha = (const float*)d_in[10];
    const float* thr_c = (const float*)d_in[11];
    const float* stp = (const float*)d_in[12];

    char* ws = (char*)d_ws;
    u16* f16heap = (u16*)ws;
    u16* hb     = f16heap + 0;         // 2048x1024       ( 0..4MB)
    u16* Wqh    = f16heap + 2097152;   // 1024x1024       ( 4..6MB)
    u16* Wkh    = f16heap + 3145728;   //                 ( 6..8MB)
    u16* Wvh    = f16heap + 4194304;   //                 ( 8..10MB)
    u16* Woh    = f16heap + 5242880;   //                 (10..12MB)
    u16* Wprojh = f16heap + 6291456;   // 1024x4096       (12..20MB)
    u16* Wfch   = f16heap + 10485760;  // 8192x1024       (20..36MB)
    u16* partsP = Wfch;                // proj partials 4x(2048x1024), after Wfc dead
    u16* qb   = (u16*)(ws + (size_t)36 * MB);
    u16* kb   = (u16*)(ws + (size_t)40 * MB);
    u16* vb   = (u16*)(ws + (size_t)44 * MB);
    u16* y    = (u16*)(ws + (size_t)48 * MB);
    float* yp = (float*)(ws + (size_t)52 * MB);   // 2 x 8MB f32 attn partials (52..68)
    f32x2* mden = (f32x2*)(ws + (size_t)68 * MB); // 512KB
    u16* hattP = (u16*)(ws + (size_t)52 * MB);    // Wo partials 4x4MB (52..68; yp dead post-merge)
    float* h1 = (float*)(ws + (size_t)36 * MB);   // 36..44 (qb/kb dead post-attn)
    u16* h1h  = (u16*)(ws + (size_t)44 * MB);     // 44..48 (vb dead post-attn)
    u16* xmlp = (u16*)(ws + (size_t)52 * MB);     // 52..68 (hattP dead post-normres1)
    float* out = (float*)d_out;

    cvt_kernel<<<9216, 256, 0, stream>>>(h, Wq, Wk, Wv, Wo, Wfc, Wproj, f16heap);
    qkv_h_kernel<<<dim3(8, 16, 3), 256, 0, stream>>>(hb, Wqh, Wkh, Wvh, qb, kb, vb);
    qkprep_kernel<<<dim3(8192, 1, 2), 256, 0, stream>>>(qb, kb, sqk);
    attn_kernel<<<dim3(64, 32), 128, 0, stream>>>(qb, kb, vb, thr_c, stp, yp, mden);
    attn_merge_kernel<<<2048, 256, 0, stream>>>(yp, mden, y);
    gemm_h_kernel<<<dim3(8, 16, 4), 256, 0, stream>>>(y, Woh, hattP, 1024, 256, 2097152, 1024);
    normres_kernel<<<2048, 256, 0, stream>>>(h, hattP, 4, 2097152, attn_alpha, h1, h1h);
    fc_silu_kernel<<<dim3(32, 16), 256, 0, stream>>>(h1h, Wfch, suv, xmlp);
    gemm_h_kernel<<<dim3(8, 16, 4), 256, 0, stream>>>(xmlp, Wprojh, partsP, 4096, 1024, 2097152, 1024);
    normres_kernel<<<2048, 256, 0, stream>>>(h1, partsP, 4, 2097152, mlp_alpha, out, (u16*)nullptr);
}

// Round 8
// 203.542 us; speedup vs baseline: 2.3478x; 1.0116x over previous
//
#include <hip/hip_runtime.h>
#include <hip/hip_bf16.h>
#include <math.h>

typedef _Float16 f16x8 __attribute__((ext_vector_type(8)));
typedef float f32x4 __attribute__((ext_vector_type(4)));
typedef float f32x2 __attribute__((ext_vector_type(2)));
typedef unsigned short u16;
typedef unsigned int u32;
typedef u16 u16x4 __attribute__((ext_vector_type(4)));
typedef u16 u16x8 __attribute__((ext_vector_type(8)));

#define DEVI static __device__ __forceinline__
#define LDSS 72  // attn LDS row stride (16B-aligned pad)
#define MB (1u << 20)

DEVI u16 f2h(float f) {
    _Float16 h = (_Float16)f;
    return __builtin_bit_cast(u16, h);
}
DEVI float h2f(u16 u) {
    return (float)__builtin_bit_cast(_Float16, u);
}
DEVI f32x4 mfma16(f16x8 a, f16x8 b, f32x4 c) {
    return __builtin_amdgcn_mfma_f32_16x16x32_f16(a, b, c, 0, 0, 0);
}
DEVI void gload16(const u16* g, u16* l) {
    __builtin_amdgcn_global_load_lds((const __attribute__((address_space(1))) void*)g,
                                     (__attribute__((address_space(3))) void*)l, 16, 0, 0);
}

// stage a 128x64 f16 tile global -> LDS (linear [128][64]) via global_load_lds.
DEVI void stage128(const u16* __restrict__ g, size_t row0, int ldg, int k0, u16* lds) {
    int t = threadIdx.x;
    const u16* src = g + (row0 + (size_t)(t >> 3)) * (size_t)ldg + k0 + (t & 7) * 8;
    u16* dst = lds + (t >> 6) * 512;  // wave-uniform
#pragma unroll
    for (int is = 0; is < 4; is++)
        gload16(src + (size_t)is * 32 * ldg, dst + is * 2048);
}

// ---------------- 128x128 MFMA core: C[m,n] = sum_k A[m,k]*B[n,k], f16 in ----------------
DEVI void gemm128_core(const u16* __restrict__ A, const u16* __restrict__ B,
                       int ldk, int kbeg, int kend, int m0, int n0,
                       u16* As, u16* Bs, f32x4 acc[4][4]) {
    int lane = threadIdx.x & 63, w = threadIdx.x >> 6;
    int wm = (w >> 1) * 64, wn = (w & 1) * 64;
    int lrow = lane & 15, lg = lane >> 4;
    for (int k0 = kbeg; k0 < kend; k0 += 64) {
        __syncthreads();
        stage128(A, m0, ldk, k0, As);
        stage128(B, n0, ldk, k0, Bs);
        __syncthreads();
#pragma unroll
        for (int ks = 0; ks < 2; ks++) {
            f16x8 af[4], bf[4];
#pragma unroll
            for (int i = 0; i < 4; i++) {
                af[i] = *reinterpret_cast<f16x8*>(&As[(wm + i * 16 + lrow) * 64 + ks * 32 + lg * 8]);
                bf[i] = *reinterpret_cast<f16x8*>(&Bs[(wn + i * 16 + lrow) * 64 + ks * 32 + lg * 8]);
            }
#pragma unroll
            for (int i = 0; i < 4; i++)
#pragma unroll
                for (int j = 0; j < 4; j++)
                    acc[i][j] = mfma16(af[i], bf[j], acc[i][j]);
        }
    }
}

// ---------------- fp32 -> f16 one-time conversion of h + all weights ----------------
__global__ void cvt_kernel(const float* __restrict__ h, const float* __restrict__ Wq,
                           const float* __restrict__ Wk, const float* __restrict__ Wv,
                           const float* __restrict__ Wo, const float* __restrict__ Wfc,
                           const float* __restrict__ Wproj, u16* __restrict__ dst) {
    int bid = blockIdx.x;
    const float* src;
    size_t doff;
    int sb;
    if (bid < 1024)      { src = h;     sb = 0;    doff = 0; }
    else if (bid < 1536) { src = Wq;    sb = 1024; doff = 2097152; }
    else if (bid < 2048) { src = Wk;    sb = 1536; doff = 3145728; }
    else if (bid < 2560) { src = Wv;    sb = 2048; doff = 4194304; }
    else if (bid < 3072) { src = Wo;    sb = 2560; doff = 5242880; }
    else if (bid < 7168) { src = Wfc;   sb = 3072; doff = 10485760; }
    else                 { src = Wproj; sb = 7168; doff = 6291456; }
    size_t idx = (size_t)(bid - sb) * 2048 + threadIdx.x * 8;
    f32x4 a = *reinterpret_cast<const f32x4*>(src + idx);
    f32x4 b = *reinterpret_cast<const f32x4*>(src + idx + 4);
    u16x8 o;
    o[0] = f2h(a[0]); o[1] = f2h(a[1]); o[2] = f2h(a[2]); o[3] = f2h(a[3]);
    o[4] = f2h(b[0]); o[5] = f2h(b[1]); o[6] = f2h(b[2]); o[7] = f2h(b[3]);
    *reinterpret_cast<u16x8*>(dst + doff + idx) = o;
}

// ---------------- QKV ----------------
__global__ __launch_bounds__(256, 2) void qkv_h_kernel(
    const u16* __restrict__ hb, const u16* __restrict__ Wqh, const u16* __restrict__ Wkh,
    const u16* __restrict__ Wvh, u16* __restrict__ qb, u16* __restrict__ kb, u16* __restrict__ vb) {
    __shared__ u16 As[128 * 64];
    __shared__ u16 Bs[128 * 64];
    int z = blockIdx.z;
    const u16* W = (z == 0) ? Wqh : (z == 1) ? Wkh : Wvh;
    u16* dst = (z == 0) ? qb : (z == 1) ? kb : vb;
    int m0 = blockIdx.y * 128, n0 = blockIdx.x * 128;
    f32x4 acc[4][4];
    f32x4 zf = {0.f, 0.f, 0.f, 0.f};
#pragma unroll
    for (int i = 0; i < 4; i++)
#pragma unroll
        for (int j = 0; j < 4; j++) acc[i][j] = zf;
    gemm128_core(hb, W, 1024, 0, 1024, m0, n0, As, Bs, acc);
    int lane = threadIdx.x & 63, w = threadIdx.x >> 6;
    int wm = (w >> 1) * 64, wn = (w & 1) * 64;
    int lrow = lane & 15, lg = lane >> 4;
#pragma unroll
    for (int i = 0; i < 4; i++)
#pragma unroll
        for (int j = 0; j < 4; j++)
#pragma unroll
            for (int r = 0; r < 4; r++) {
                int m = m0 + wm + i * 16 + lg * 4 + r;
                int n = n0 + wn + j * 16 + lrow;
                dst[(size_t)m * 1024 + n] = f2h(acc[i][j][r]);
            }
}

// ---------------- generic 128x128 GEMM, f16 out, optional K-split via grid.z ----------------
__global__ __launch_bounds__(256, 2) void gemm_h_kernel(
    const u16* __restrict__ A, const u16* __restrict__ B, u16* __restrict__ out,
    int ldk, int ksplit, int osplit, int N) {
    __shared__ u16 As[128 * 64];
    __shared__ u16 Bs[128 * 64];
    int z = blockIdx.z;
    int m0 = blockIdx.y * 128, n0 = blockIdx.x * 128;
    f32x4 acc[4][4];
    f32x4 zf = {0.f, 0.f, 0.f, 0.f};
#pragma unroll
    for (int i = 0; i < 4; i++)
#pragma unroll
        for (int j = 0; j < 4; j++) acc[i][j] = zf;
    gemm128_core(A, B, ldk, z * ksplit, (z + 1) * ksplit, m0, n0, As, Bs, acc);
    u16* o = out + (size_t)z * osplit;
    int lane = threadIdx.x & 63, w = threadIdx.x >> 6;
    int wm = (w >> 1) * 64, wn = (w & 1) * 64;
    int lrow = lane & 15, lg = lane >> 4;
#pragma unroll
    for (int i = 0; i < 4; i++)
#pragma unroll
        for (int j = 0; j < 4; j++)
#pragma unroll
            for (int r = 0; r < 4; r++) {
                int m = m0 + wm + i * 16 + lg * 4 + r;
                int n = n0 + wn + j * 16 + lrow;
                o[(size_t)m * N + n] = f2h(acc[i][j][r]);
            }
}

// ---------------- RoPE + L2 norm + sqk scale, f16 in-place ----------------
__global__ void qkprep_kernel(u16* __restrict__ qb, u16* __restrict__ kb,
                              const float* __restrict__ sqk) {
    u16* buf = blockIdx.z ? kb : qb;
    int pair = blockIdx.x * 4 + (threadIdx.x >> 6);  // (m,h) pair
    int m = pair >> 4, hh = pair & 15;
    int tt = m & 1023;  // t = m % T
    int d = threadIdx.x & 63;
    size_t off = (size_t)m * 1024 + hh * 64 + d;
    float x = h2f(buf[off]);
    float xn = __shfl_xor(x, 1);
    int j = (d & 1) ? ((d - 1) >> 1) : (32 + (d >> 1));
    float dv = exp2f(-(float)(j >> 1) * 0.41524101186092029f);  // log2(10000)/32
    float ang = (float)tt * dv;
    float e = (j & 1) ? cosf(ang) : sinf(ang);
    float xr = (d & 1) ? (xn * e) : (-xn * e);
    float ss = xr * xr;
#pragma unroll
    for (int o = 1; o < 64; o <<= 1) ss += __shfl_xor(ss, o);
    float sc = rsqrtf(ss) * sqk[hh * 64 + d] * 32.0f;
    buf[off] = f2h(xr * sc);
}

// ---------------- flash attention, split-KV x4, gate folded into softmax ----------------
// Round-6-validated structure: Vt LDS double-buffer (explicit bufsel), register K/V
// prefetch one owned-tile ahead, ONE barrier per tile, branch-free softmax:
// p = exp(s - m) * rcp(1 + exp(st*(thr-s))); m = max(s) - softplus(st*(thr - max s)).
// f16 unnormalized partials + (m, den) per q-row; merged by attn_merge_kernel.
__global__ __launch_bounds__(128) void attn_kernel(
    const u16* __restrict__ qb, const u16* __restrict__ kb, const u16* __restrict__ vb,
    const float* __restrict__ thr_c, const float* __restrict__ stp,
    u16* __restrict__ yph, f32x2* __restrict__ mden) {
    const int T = 1024, C = 1024;
    int qt = 31 - (blockIdx.x >> 2);  // heavy-first
    int c = blockIdx.x & 3;           // kv chunk (stride-4 tiles)
    int bh = blockIdx.y;
    int b = bh >> 4, hh = bh & 15;
    int q0 = qt * 32;
    int nkt = (q0 >> 6) + 1;
    __shared__ u16 Vt[2][64 * LDSS];  // double-buffered transposed V
    __shared__ u16 Ps[32 * LDSS];     // P[q_local][kv] (wave-private rows)
    int t = threadIdx.x;
    int lane = t & 63, w = t >> 6;
    int lrow = lane & 15, lg = lane >> 4, lk = lg * 8;
    int kvp = t & 31, db = t >> 5;    // V-stage lane mapping

    // Q fragments straight from global (L2-resident)
    const u16* qrowp = qb + (size_t)(b * T + q0 + w * 16 + lrow) * C + hh * 64;
    f16x8 qfr[2];
    qfr[0] = *reinterpret_cast<const f16x8*>(qrowp + lk);
    qfr[1] = *reinterpret_cast<const f16x8*>(qrowp + 32 + lk);

    float thr = thr_c[hh], st = stp[hh];
    float stthr = st * thr;
    float mrun = -1e30f, den = 0.f;
    f32x4 yacc[4];
    f32x4 zf = {0.f, 0.f, 0.f, 0.f};
#pragma unroll
    for (int i = 0; i < 4; i++) yacc[i] = zf;
    int qg = q0 + w * 16 + lrow;

    f16x8 kpre[8];   // prefetched K fragments
    u16x4 vr[8];     // prefetched V rows (2 kv rows x 16 d)
    const u16* kbase0 = kb + (size_t)(b * T + lrow) * C + hh * 64 + lk;
    const u16* vbase0 = vb + (size_t)(b * T + 2 * kvp) * C + hh * 64 + db * 16;

    if (c < nkt) {  // prologue prefetch of tile c
        const u16* kbase = kbase0 + (size_t)(c << 6) * C;
        const u16* vsrc = vbase0 + (size_t)(c << 6) * C;
#pragma unroll
        for (int ks = 0; ks < 2; ks++)
#pragma unroll
            for (int f = 0; f < 4; f++)
                kpre[ks * 4 + f] = *reinterpret_cast<const f16x8*>(kbase + (size_t)(f * 16) * C + ks * 32);
#pragma unroll
        for (int dd = 0; dd < 4; dd++) {
            vr[dd * 2] = *reinterpret_cast<const u16x4*>(vsrc + dd * 4);
            vr[dd * 2 + 1] = *reinterpret_cast<const u16x4*>(vsrc + C + dd * 4);
        }
    }

    int bufsel = 0;
    for (int kt = c; kt < nkt; kt += 4) {
        int kv0 = kt << 6;
        u16* VB = Vt[bufsel];
        bufsel ^= 1;  // explicit alternation (stride-4 safe)
        // store prefetched V (transposed) into this tile's buffer
#pragma unroll
        for (int dd = 0; dd < 4; dd++)
#pragma unroll
            for (int e = 0; e < 4; e++) {
                u32 v = (u32)vr[dd * 2][e] | ((u32)vr[dd * 2 + 1][e] << 16);
                *reinterpret_cast<u32*>(&VB[(db * 16 + dd * 4 + e) * LDSS + 2 * kvp]) = v;
            }
        // S^T = K . Q^T from prefetched K fragments
        f32x4 sacc[4];
#pragma unroll
        for (int f = 0; f < 4; f++) sacc[f] = zf;
#pragma unroll
        for (int ks = 0; ks < 2; ks++)
#pragma unroll
            for (int f = 0; f < 4; f++)
                sacc[f] = mfma16(kpre[ks * 4 + f], qfr[ks], sacc[f]);

        // prefetch tile kt+4 (latency hidden under softmax+PV)
        if (kt + 4 < nkt) {
            const u16* kbase = kbase0 + (size_t)((kt + 4) << 6) * C;
            const u16* vsrc = vbase0 + (size_t)((kt + 4) << 6) * C;
#pragma unroll
            for (int ks = 0; ks < 2; ks++)
#pragma unroll
                for (int f = 0; f < 4; f++)
                    kpre[ks * 4 + f] = *reinterpret_cast<const f16x8*>(kbase + (size_t)(f * 16) * C + ks * 32);
#pragma unroll
            for (int dd = 0; dd < 4; dd++) {
                vr[dd * 2] = *reinterpret_cast<const u16x4*>(vsrc + dd * 4);
                vr[dd * 2 + 1] = *reinterpret_cast<const u16x4*>(vsrc + C + dd * 4);
            }
        }

        // ----- softmax (branch-free) -----
        float svv[16];
        float tmax = -1e30f;
        bool last = (kt == nkt - 1);
#pragma unroll
        for (int f = 0; f < 4; f++)
#pragma unroll
            for (int r = 0; r < 4; r++) {
                float s = sacc[f][r] * 8.0f;  // * sqrt(D)
                if (last) {
                    int kvg = kv0 + f * 16 + lg * 4 + r;
                    if (kvg > qg) s = -1e30f;
                }
                svv[f * 4 + r] = s;
                tmax = fmaxf(tmax, s);
            }
        tmax = fmaxf(tmax, __shfl_xor(tmax, 16));
        tmax = fmaxf(tmax, __shfl_xor(tmax, 32));
        // row max of gated score via monotonicity (single softplus)
        float zM = stthr - st * tmax;
        float spM = tmax - __logf(1.0f + __expf(zM));
        float mnew = fmaxf(mrun, spM);
        float alpha = __expf(mrun - mnew);
        float tden = 0.f;
        u16 pu[16];
#pragma unroll
        for (int i = 0; i < 16; i++) {
            float s = svv[i];
            float e2 = __expf(s - mnew);
            float eg = __expf(stthr - st * s);
            float p = e2 * __builtin_amdgcn_rcpf(1.0f + eg);
            u16 ph = f2h(p);
            pu[i] = ph;
            tden += h2f(ph);  // denominator from quantized P: rounding cancels
        }
        tden += __shfl_xor(tden, 16);
        tden += __shfl_xor(tden, 32);
        den = den * alpha + tden;
        mrun = mnew;

#pragma unroll
        for (int f = 0; f < 4; f++) {
            u16x4 u = {pu[f * 4 + 0], pu[f * 4 + 1], pu[f * 4 + 2], pu[f * 4 + 3]};
            *reinterpret_cast<u16x4*>(&Ps[(w * 16 + lrow) * LDSS + f * 16 + lg * 4]) = u;
        }
        float a4[4];
#pragma unroll
        for (int r = 0; r < 4; r++) a4[r] = __shfl(alpha, lg * 4 + r);
#pragma unroll
        for (int nf = 0; nf < 4; nf++)
#pragma unroll
            for (int r = 0; r < 4; r++) yacc[nf][r] *= a4[r];

        __syncthreads();  // VB staged; single barrier per tile (dbuf removes WAR hazard)

        // PV (P rows wave-private; lgkmcnt orders ds write->read)
#pragma unroll
        for (int ks = 0; ks < 2; ks++) {
            f16x8 pf = *reinterpret_cast<f16x8*>(&Ps[(w * 16 + lrow) * LDSS + ks * 32 + lk]);
#pragma unroll
            for (int nf = 0; nf < 4; nf++) {
                f16x8 vf = *reinterpret_cast<f16x8*>(&VB[(nf * 16 + lrow) * LDSS + ks * 32 + lk]);
                yacc[nf] = mfma16(pf, vf, yacc[nf]);
            }
        }
    }
    // store partials: unnormalized y (f16) + (m, den)
    u16* ypc = yph + (size_t)c * 2097152;
#pragma unroll
    for (int nf = 0; nf < 4; nf++)
#pragma unroll
        for (int r = 0; r < 4; r++) {
            int qrow = q0 + w * 16 + lg * 4 + r;
            ypc[(size_t)(b * T + qrow) * C + hh * 64 + nf * 16 + lrow] = f2h(yacc[nf][r]);
        }
    if (lg == 0) {
        f32x2 md;
        md[0] = mrun; md[1] = den;
        mden[((size_t)c * 32 + bh) * 1024 + (q0 + w * 16 + lrow)] = md;
    }
}

// ---------------- merge 4 split-KV partials -> normalized f16 y ----------------
__global__ void attn_merge_kernel(const u16* __restrict__ yph, const f32x2* __restrict__ mden,
                                  u16* __restrict__ y) {
    int row = blockIdx.x;  // b*T + t
    int b = row >> 10, tr = row & 1023;
    int t = threadIdx.x;
#pragma unroll
    for (int i = 0; i < 4; i++) {
        int idx = t + 256 * i;
        int hh = idx >> 6;
        float m[4], d[4];
        float M = -1e30f;
#pragma unroll
        for (int p = 0; p < 4; p++) {
            f32x2 md = mden[((size_t)p * 32 + b * 16 + hh) * 1024 + tr];
            m[p] = md[0]; d[p] = md[1];
            M = fmaxf(M, m[p]);
        }
        size_t off = (size_t)row * 1024 + idx;
        float dn = 0.f, acc = 0.f;
#pragma unroll
        for (int p = 0; p < 4; p++) {
            float wp = __expf(m[p] - M);
            dn += d[p] * wp;
            acc += h2f(yph[off + (size_t)p * 2097152]) * wp;
        }
        y[off] = f2h(acc / dn);
    }
}

// ---------------- FC (u and v halves) + SiLU gate fused, 128x128 tile ----------------
__global__ __launch_bounds__(256, 2) void fc_silu_kernel(
    const u16* __restrict__ h1h, const u16* __restrict__ Wfch,
    const float* __restrict__ suv, u16* __restrict__ xmlp) {
    __shared__ u16 As[128 * 64];
    __shared__ u16 Bu[128 * 64];
    __shared__ u16 Bv[128 * 64];
    int m0 = blockIdx.y * 128, n0 = blockIdx.x * 128;
    f32x4 au[4][4], av[4][4];
    f32x4 zf = {0.f, 0.f, 0.f, 0.f};
#pragma unroll
    for (int i = 0; i < 4; i++)
#pragma unroll
        for (int j = 0; j < 4; j++) { au[i][j] = zf; av[i][j] = zf; }
    int lane = threadIdx.x & 63, w = threadIdx.x >> 6;
    int wm = (w >> 1) * 64, wn = (w & 1) * 64;
    int lrow = lane & 15, lg = lane >> 4;
    for (int k0 = 0; k0 < 1024; k0 += 64) {
        __syncthreads();
        stage128(h1h, m0, 1024, k0, As);
        stage128(Wfch, n0, 1024, k0, Bu);
        stage128(Wfch, 4096 + n0, 1024, k0, Bv);
        __syncthreads();
#pragma unroll
        for (int ks = 0; ks < 2; ks++) {
            f16x8 af[4], bu[4], bv[4];
#pragma unroll
            for (int i = 0; i < 4; i++) {
                af[i] = *reinterpret_cast<f16x8*>(&As[(wm + i * 16 + lrow) * 64 + ks * 32 + lg * 8]);
                bu[i] = *reinterpret_cast<f16x8*>(&Bu[(wn + i * 16 + lrow) * 64 + ks * 32 + lg * 8]);
                bv[i] = *reinterpret_cast<f16x8*>(&Bv[(wn + i * 16 + lrow) * 64 + ks * 32 + lg * 8]);
            }
#pragma unroll
            for (int i = 0; i < 4; i++)
#pragma unroll
                for (int j = 0; j < 4; j++) {
                    au[i][j] = mfma16(af[i], bu[j], au[i][j]);
                    av[i][j] = mfma16(af[i], bv[j], av[i][j]);
                }
        }
    }
#pragma unroll
    for (int i = 0; i < 4; i++)
#pragma unroll
        for (int j = 0; j < 4; j++) {
            int n = n0 + wn + j * 16 + lrow;
            float su = suv[n] * 32.0f;
            float sv = suv[4096 + n] * 32.0f;
#pragma unroll
            for (int r = 0; r < 4; r++) {
                int m = m0 + wm + i * 16 + lg * 4 + r;
                float uu = au[i][j][r] * su;
                float vv = av[i][j][r] * sv;
                float sig = 1.0f / (1.0f + __expf(-vv));
                xmlp[(size_t)m * 4096 + n] = f2h(uu * vv * sig);
            }
        }
}

// ---------------- justnorm residual-lerp-justnorm; delta = sum of f16 parts ----------------
__global__ void normres_kernel(const float* __restrict__ base, const u16* __restrict__ dparts,
                               int nparts, int pstride, const float* __restrict__ alpha,
                               float* __restrict__ outf, u16* __restrict__ outh) {
    int row = blockIdx.x;
    int t = threadIdx.x;
    const float* pb = base + (size_t)row * 1024;
    float xb[4], xd[4];
    float ssb = 0.f, ssd = 0.f;
#pragma unroll
    for (int i = 0; i < 4; i++) {
        size_t off = (size_t)row * 1024 + t + 256 * i;
        xb[i] = pb[t + 256 * i];
        float d = 0.f;
        for (int p = 0; p < nparts; p++) d += h2f(dparts[off + (size_t)p * pstride]);
        xd[i] = d;
        ssb += xb[i] * xb[i];
        ssd += xd[i] * xd[i];
    }
#pragma unroll
    for (int o = 1; o < 64; o <<= 1) { ssb += __shfl_xor(ssb, o); ssd += __shfl_xor(ssd, o); }
    __shared__ float red[8];
    int w = t >> 6;
    if ((t & 63) == 0) { red[w * 2] = ssb; red[w * 2 + 1] = ssd; }
    __syncthreads();
    ssb = red[0] + red[2] + red[4] + red[6];
    ssd = red[1] + red[3] + red[5] + red[7];
    float rb = rsqrtf(ssb), rd = rsqrtf(ssd);
    float c[4];
    float ssc = 0.f;
#pragma unroll
    for (int i = 0; i < 4; i++) {
        float a = xb[i] * rb;
        float bb = xd[i] * rd;
        float lr = fabsf(alpha[t + 256 * i] * 1.6f);  // 0.05/0.03125
        float cv = a + lr * (bb - a);
        c[i] = cv;
        ssc += cv * cv;
    }
#pragma unroll
    for (int o = 1; o < 64; o <<= 1) ssc += __shfl_xor(ssc, o);
    __syncthreads();
    if ((t & 63) == 0) red[w] = ssc;
    __syncthreads();
    ssc = red[0] + red[1] + red[2] + red[3];
    float rc = rsqrtf(ssc);
#pragma unroll
    for (int i = 0; i < 4; i++) {
        float v = c[i] * rc;
        size_t off = (size_t)row * 1024 + t + 256 * i;
        outf[off] = v;
        if (outh) outh[off] = f2h(v);
    }
}

extern "C" void kernel_launch(void* const* d_in, const int* in_sizes, int n_in,
                              void* d_out, int out_size, void* d_ws, size_t ws_size,
                              hipStream_t stream) {
    const float* h = (const float*)d_in[0];
    const float* Wq = (const float*)d_in[1];
    const float* Wk = (const float*)d_in[2];
    const float* Wv = (const float*)d_in[3];
    const float* Wo = (const float*)d_in[4];
    const float* Wfc = (const float*)d_in[5];
    const float* Wproj = (const float*)d_in[6];
    const float* sqk = (const float*)d_in[7];
    const float* suv = (const float*)d_in[8];
    const float* attn_alpha = (const float*)d_in[9];
    const float* mlp_alpha = (const float*)d_in[10];
    const float* thr_c = (const float*)d_in[11];
    const float* stp = (const float*)d_in[12];

    char* ws = (char*)d_ws;
    u16* f16heap = (u16*)ws;
    u16* hb     = f16heap + 0;         // 2048x1024       ( 0..4MB)
    u16* Wqh    = f16heap + 2097152;   // 1024x1024       ( 4..6MB)
    u16* Wkh    = f16heap + 3145728;   //                 ( 6..8MB)
    u16* Wvh    = f16heap + 4194304;   //                 ( 8..10MB)
    u16* Woh    = f16heap + 5242880;   //                 (10..12MB)
    u16* Wprojh = f16heap + 6291456;   // 1024x4096       (12..20MB)
    u16* Wfch   = f16heap + 10485760;  // 8192x1024       (20..36MB)
    u16* partsP = Wfch;                // proj partials 4x(2048x1024), after Wfc dead
    u16* qb   = (u16*)(ws + (size_t)36 * MB);
    u16* kb   = (u16*)(ws + (size_t)40 * MB);
    u16* vb   = (u16*)(ws + (size_t)44 * MB);
    u16* y    = (u16*)(ws + (size_t)48 * MB);     // merged attn out (48..52)
    u16* yph  = (u16*)(ws + (size_t)52 * MB);     // 4 x 4MB f16 attn partials (52..68)
    f32x2* mden = (f32x2*)(ws + (size_t)68 * MB); // 1MB (68..69)
    u16* hattP = (u16*)(ws + (size_t)52 * MB);    // Wo partials 4x4MB (52..68; yph dead post-merge)
    float* h1 = (float*)(ws + (size_t)36 * MB);   // 36..44 (qb/kb dead post-attn)
    u16* h1h  = (u16*)(ws + (size_t)44 * MB);     // 44..48 (vb dead post-attn)
    u16* xmlp = (u16*)(ws + (size_t)52 * MB);     // 52..68 (hattP dead post-normres1)
    float* out = (float*)d_out;

    cvt_kernel<<<9216, 256, 0, stream>>>(h, Wq, Wk, Wv, Wo, Wfc, Wproj, f16heap);
    qkv_h_kernel<<<dim3(8, 16, 3), 256, 0, stream>>>(hb, Wqh, Wkh, Wvh, qb, kb, vb);
    qkprep_kernel<<<dim3(8192, 1, 2), 256, 0, stream>>>(qb, kb, sqk);
    attn_kernel<<<dim3(128, 32), 128, 0, stream>>>(qb, kb, vb, thr_c, stp, yph, mden);
    attn_merge_kernel<<<2048, 256, 0, stream>>>(yph, mden, y);
    gemm_h_kernel<<<dim3(8, 16, 4), 256, 0, stream>>>(y, Woh, hattP, 1024, 256, 2097152, 1024);
    normres_kernel<<<2048, 256, 0, stream>>>(h, hattP, 4, 2097152, attn_alpha, h1, h1h);
    fc_silu_kernel<<<dim3(32, 16), 256, 0, stream>>>(h1h, Wfch, suv, xmlp);
    gemm_h_kernel<<<dim3(8, 16, 4), 256, 0, stream>>>(xmlp, Wprojh, partsP, 4096, 1024, 2097152, 1024);
    normres_kernel<<<2048, 256, 0, stream>>>(h1, partsP, 4, 2097152, mlp_alpha, out, (u16*)nullptr);
}